// Round 15
// baseline (981.137 us; speedup 1.0000x reference)
//
#include <hip/hip_runtime.h>
#include <hip/hip_cooperative_groups.h>
#include <math.h>

#define NEGV (-1e9f)
#define LOG2E 1.4426950408889634f

namespace cg = cooperative_groups;

typedef _Float16 f16;
typedef __attribute__((ext_vector_type(2))) __fp16 hf2;
typedef __attribute__((ext_vector_type(4))) _Float16 f16x4;
typedef __attribute__((ext_vector_type(4))) float f32x4;

struct MP {
    const float *r1, *r2, *edge;
    const float *d1_wqkv, *d1_bqkv, *d1_wo, *d1_bo;
    const float *d2_wqkv, *d2_bqkv, *d2_wo, *d2_bo;
    const float *pol_wqkv, *pol_bqkv, *pol_wo, *pol_bo;
    const float *val_wqkv, *val_bqkv, *val_wo, *val_bo;
    const float *v2_w, *v2_b;
    const int* mask;
    f16 *q1h, *k1h, *v1h, *q2h, *k2h, *v2h, *qph, *kph, *vph, *qvh, *kvh, *vvh;
    float *pacc, *plp, *plv;
    float *Wf1, *bf1, *Wfp, *bfp, *Wfv, *bfv;
    float *paccp, *paccv;
    float *out_action, *out_critic;
    float qmul1, qmul2;
};

static const int CB = 16, CM = 32, CF = 16, CH = 4;
static const int CN = 1024, CBN = 16384;

// ---------------------------------------------------------------------------
// P1: vb < 9216 -> d1 feature-build + QKV (f16 head-major, Q pre-scaled);
//     vb in [9216, 9232) -> folded-weight prep.
// ---------------------------------------------------------------------------
__device__ void phase_qkv1_prep(const MP& P, int vb) {
    const int N = CN, BN = CBN, M = CM, F = CF, H = CH;
    if (vb < 9216) {
        int t = vb * 256 + threadIdx.x;          // t < 3*BN*48 exactly
        int col = t % 48;
        int row = (t / 48) % BN;
        int mat = t / (48 * BN);
        int b = row / N, n = row % N;
        int i = n / M, j = n % M;

        const float* f1 = P.r1 + (b * M + i) * F;
        const float* f2 = P.r2 + (b * M + j) * F;
        const float* fe = P.edge + (size_t)row * F;
        const float* w  = P.d1_wqkv + mat * 48 * 48 + col;

        float s = P.d1_bqkv[mat * 48 + col];
#pragma unroll
        for (int d = 0; d < 16; ++d) s = fmaf(f1[d], w[d * 48], s);
#pragma unroll
        for (int d = 0; d < 16; ++d) s = fmaf(f2[d], w[(16 + d) * 48], s);
#pragma unroll
        for (int d = 0; d < 16; ++d) s = fmaf(fe[d], w[(32 + d) * 48], s);

        int h = col / 12, dd = col % 12;
        size_t off = ((size_t)(b * H + h) * N + n) * 12 + dd;
        if (mat == 0)      P.q1h[off] = (f16)(s * P.qmul1);
        else if (mat == 1) P.k1h[off] = (f16)s;
        else               P.v1h[off] = (f16)s;
        return;
    }

    int t = (vb - 9216) * 256 + threadIdx.x;
    if (t < 2304) {                     // Wf1
        int mat = t / 768, r = (t % 768) / 16, c = t % 16;
        float s = 0.f;
#pragma unroll
        for (int k = 0; k < 16; ++k)
            s = fmaf(P.d1_wo[r * 16 + k], P.d2_wqkv[mat * 256 + k * 16 + c], s);
        P.Wf1[t] = s;
        return;
    }
    int u = t - 2304;
    if (u < 48) {                       // bf1
        int mat = u / 16, c = u % 16;
        float s = P.d2_bqkv[mat * 16 + c];
#pragma unroll
        for (int k = 0; k < 16; ++k)
            s = fmaf(P.d1_bo[k], P.d2_wqkv[mat * 256 + k * 16 + c], s);
        P.bf1[u] = s;
        return;
    }
    u -= 48;
    if (u < 768) {                      // Wfp
        int mat = u / 256, r = (u % 256) / 16, c = u % 16;
        float s = 0.f;
#pragma unroll
        for (int k = 0; k < 16; ++k)
            s = fmaf(P.d2_wo[r * 16 + k], P.pol_wqkv[mat * 256 + k * 16 + c], s);
        P.Wfp[u] = s;
        return;
    }
    u -= 768;
    if (u < 48) {                       // bfp
        int mat = u / 16, c = u % 16;
        float s = P.pol_bqkv[mat * 16 + c];
#pragma unroll
        for (int k = 0; k < 16; ++k)
            s = fmaf(P.d2_bo[k], P.pol_wqkv[mat * 256 + k * 16 + c], s);
        P.bfp[u] = s;
        return;
    }
    u -= 48;
    if (u < 768) {                      // Wfv
        int mat = u / 256, r = (u % 256) / 16, c = u % 16;
        float s = 0.f;
#pragma unroll
        for (int k = 0; k < 16; ++k)
            s = fmaf(P.d2_wo[r * 16 + k], P.val_wqkv[mat * 256 + k * 16 + c], s);
        P.Wfv[u] = s;
        return;
    }
    u -= 768;
    if (u < 48) {                       // bfv
        int mat = u / 16, c = u % 16;
        float s = P.val_bqkv[mat * 16 + c];
#pragma unroll
        for (int k = 0; k < 16; ++k)
            s = fmaf(P.d2_bo[k], P.val_wqkv[mat * 256 + k * 16 + c], s);
        P.bfv[u] = s;
    }
}

// ---------------------------------------------------------------------------
// Attention phase (R14 attn_h_kernel body, QT=2), smem-arena version.
// bx in [0, BH) or [0, 2BH) (two sets), by in [0,8), bz in [0,4).
// ---------------------------------------------------------------------------
template <int DH>
__device__ void phase_attn(const f16* __restrict__ qh1, const f16* __restrict__ kh1,
                           const f16* __restrict__ vh1,
                           const f16* __restrict__ qh2, const f16* __restrict__ kh2,
                           const f16* __restrict__ vh2,
                           const int* __restrict__ mask,
                           float* __restrict__ pacc1, float* __restrict__ pl1,
                           float* __restrict__ pacc2, float* __restrict__ pl2,
                           int bx, int by, int bz, char* smem) {
    const int H = CH, N = CN, B = CB;
    const int LD = H * DH;
    const int BH = B * H;

    f16 (*Kt)[DH]  = (f16(*)[DH])smem;                           // [256][DH]
    f16 (*Vt)[264] = (f16(*)[264])(smem + 256 * DH * 2);         // [16][264]
    float* mbs     = (float*)(smem + 256 * DH * 2 + 16 * 264 * 2);

    int bhs = bx;
    const f16* qh; const f16* kh; const f16* vh;
    float* pacc; float* pl;
    if (bhs < BH) { qh = qh1; kh = kh1; vh = vh1; pacc = pacc1; pl = pl1; }
    else          { qh = qh2; kh = kh2; vh = vh2; pacc = pacc2; pl = pl2; bhs -= BH; }
    int b = bhs / H, h = bhs % H;
    int kbase = bz * 256;
    int bN = b * N;

    int tid = threadIdx.x;
    {
        int kk = tid;
        const f16* kB = kh + ((size_t)bhs * N + kbase) * DH;
        const f16* vB = vh + ((size_t)bhs * N + kbase) * DH;
#pragma unroll
        for (int d = 0; d < DH / 4; ++d)
            ((uint2*)&Kt[kk][0])[d] = ((const uint2*)(kB + (size_t)kk * DH))[d];
        uint2 vr[DH / 4];
#pragma unroll
        for (int d = 0; d < DH / 4; ++d)
            vr[d] = ((const uint2*)(vB + (size_t)kk * DH))[d];
        const f16* vv = (const f16*)vr;
#pragma unroll
        for (int d = 0; d < DH; ++d) Vt[d][kk] = vv[d];
        Vt[DH][kk] = (f16)1.f;
        mbs[kk] = mask[bN + kbase + kk] ? (-8.f * LOG2E) : NEGV;
    }
    __syncthreads();

    int lane = tid & 63, wid = tid >> 6;
    int lrow = lane & 15, lg = lane >> 4;
    int qbase = by * 128 + wid * 32;

    const f16* qB = qh + (size_t)bhs * N * DH;
    f16x4 zf = {(f16)0.f, (f16)0.f, (f16)0.f, (f16)0.f};
    bool qok = (4 * lg < DH);
    f16x4 qf[2];
#pragma unroll
    for (int qt = 0; qt < 2; ++qt)
        qf[qt] = qok ? *(const f16x4*)(qB + (size_t)(qbase + qt * 16 + lrow) * DH + 4 * lg) : zf;

    f32x4 oacc[2];
#pragma unroll
    for (int qt = 0; qt < 2; ++qt) oacc[qt] = (f32x4){0.f, 0.f, 0.f, 0.f};

#pragma unroll 8
    for (int t16 = 0; t16 < 16; ++t16) {
        f16x4 kf = *(const f16x4*)(&Kt[0][0] + (size_t)(t16 * 16 + lrow) * DH + 4 * lg);
        float4 mv = *(const float4*)(&mbs[t16 * 16 + 4 * lg]);
        f32x4 mc = {mv.x, mv.y, mv.z, mv.w};
        f16x4 vb = *(const f16x4*)(&Vt[lrow][t16 * 16 + 4 * lg]);

#pragma unroll
        for (int qt = 0; qt < 2; ++qt) {
            f32x4 s = __builtin_amdgcn_mfma_f32_16x16x16f16(kf, qf[qt], mc, 0, 0, 0);
            hf2 lo = __builtin_amdgcn_cvt_pkrtz(__builtin_amdgcn_exp2f(s[0]),
                                                __builtin_amdgcn_exp2f(s[1]));
            hf2 hi = __builtin_amdgcn_cvt_pkrtz(__builtin_amdgcn_exp2f(s[2]),
                                                __builtin_amdgcn_exp2f(s[3]));
            f16x4 pa;
            ((hf2*)&pa)[0] = lo;
            ((hf2*)&pa)[1] = hi;
            oacc[qt] = __builtin_amdgcn_mfma_f32_16x16x16f16(pa, vb, oacc[qt], 0, 0, 0);
        }
    }

    int d = lrow;
    size_t zoff = (size_t)bz * B * N;
#pragma unroll
    for (int qt = 0; qt < 2; ++qt) {
#pragma unroll
        for (int r = 0; r < 4; ++r) {
            int q = qbase + qt * 16 + lg * 4 + r;
            float val = oacc[qt][r];
            if (d < DH)
                pacc[(zoff + bN + q) * LD + h * DH + d] = val;
            else if (d == DH)
                pl[(zoff + bN + q) * H + h] = val;
        }
    }
    __syncthreads();   // smem reuse guard for next grid-stride iteration
}

// ---------------------------------------------------------------------------
// P3: fold1 (16 rows per vb)
// ---------------------------------------------------------------------------
__device__ void phase_fold1(const MP& P, int vb, char* smem) {
    const int BN = CBN, N = CN, H = CH;
    float* comb = (float*)smem;          // [16][49]
    float* invl = comb + 16 * 49;        // [16][4]
    int row0 = vb * 16;
    int tid = threadIdx.x;
    if (tid < 64) {
        int r = tid >> 2, h = tid & 3;
        float ls = 0.f;
#pragma unroll
        for (int z = 0; z < 4; ++z) ls += P.plp[((size_t)z * BN + row0 + r) * 4 + h];
        invl[r * 4 + h] = 1.f / ls;
    }
    __syncthreads();
#pragma unroll
    for (int k = 0; k < 3; ++k) {
        int idx = tid + k * 256;
        int r = idx / 48, d = idx % 48;
        float a = 0.f;
#pragma unroll
        for (int z = 0; z < 4; ++z) a += P.pacc[((size_t)z * BN + row0 + r) * 48 + d];
        comb[r * 49 + d] = a * invl[r * 4 + d / 12];
    }
    __syncthreads();
#pragma unroll
    for (int k = 0; k < 3; ++k) {
        int idx = tid + k * 256;
        int mat = idx / 256, r = (idx % 256) / 16, c = idx % 16;
        float s = P.bf1[mat * 16 + c];
        const float* wcol = P.Wf1 + mat * 768 + c;
#pragma unroll
        for (int d = 0; d < 48; ++d)
            s = fmaf(comb[r * 49 + d], wcol[d * 16], s);
        int row = row0 + r;
        int b = row / N, n = row % N;
        int h = c >> 2, dd = c & 3;
        size_t off = ((size_t)(b * H + h) * N + n) * 4 + dd;
        if (mat == 0)      P.q2h[off] = (f16)(s * P.qmul2);
        else if (mat == 1) P.k2h[off] = (f16)s;
        else               P.v2h[off] = (f16)s;
    }
    __syncthreads();
}

// ---------------------------------------------------------------------------
// P5: fold2 (8 rows per vb)
// ---------------------------------------------------------------------------
__device__ void phase_fold2(const MP& P, int vb, char* smem) {
    const int BN = CBN, N = CN, H = CH;
    float* comb = (float*)smem;          // [8][17]
    float* invl = comb + 8 * 17;         // [8][4]
    int row0 = vb * 8;
    int tid = threadIdx.x;
    if (tid < 32) {
        int r = tid >> 2, h = tid & 3;
        float ls = 0.f;
#pragma unroll
        for (int z = 0; z < 4; ++z) ls += P.plp[((size_t)z * BN + row0 + r) * 4 + h];
        invl[r * 4 + h] = 1.f / ls;
    }
    __syncthreads();
    if (tid < 128) {
        int r = tid / 16, d = tid % 16;
        float a = 0.f;
#pragma unroll
        for (int z = 0; z < 4; ++z) a += P.pacc[((size_t)z * BN + row0 + r) * 16 + d];
        comb[r * 17 + d] = a * invl[r * 4 + (d >> 2)];
    }
    __syncthreads();
#pragma unroll
    for (int k = 0; k < 3; ++k) {
        int idx = tid + k * 256;
        int set = idx / 384;
        int rem = idx % 384;
        int mat = rem / 128, r = (rem % 128) / 16, c = rem % 16;
        const float* W  = set ? P.Wfv : P.Wfp;
        const float* bb = set ? P.bfv : P.bfp;
        float s = bb[mat * 16 + c];
        const float* wcol = W + mat * 256 + c;
#pragma unroll
        for (int d = 0; d < 16; ++d)
            s = fmaf(comb[r * 17 + d], wcol[d * 16], s);
        int row = row0 + r;
        int b = row / N, n = row % N;
        int h = c >> 2, dd = c & 3;
        size_t off = ((size_t)(b * H + h) * N + n) * 4 + dd;
        f16* dst;
        if (set == 0) dst = (mat == 0) ? P.qph : (mat == 1) ? P.kph : P.vph;
        else          dst = (mat == 0) ? P.qvh : (mat == 1) ? P.kvh : P.vvh;
        dst[off] = (f16)((mat == 0) ? s * P.qmul2 : s);
    }
    __syncthreads();
}

// ---------------------------------------------------------------------------
// P7: final (vb<B: action head + masked softmax; else value head + critic)
// ---------------------------------------------------------------------------
__device__ void phase_final(const MP& P, int vb, char* smem) {
    const int B = CB, N = CN, BN = CBN;
    int tid = threadIdx.x;
    if (vb < B) {
        int b = vb;
        int lane = tid & 63, wid = tid >> 6;
        float* wred = (float*)smem;      // [4]
        float* sbc  = wred + 4;

        float local[4];
        float mx = -INFINITY;
#pragma unroll
        for (int i = 0; i < 4; ++i) {
            int row = b * N + tid + i * 256;
            float sa = P.pol_bo[0];
            float ls0 = 0.f, ls1 = 0.f, ls2 = 0.f, ls3 = 0.f;
#pragma unroll
            for (int z = 0; z < 4; ++z) {
                const float* plr = P.plp + ((size_t)z * BN + row) * 4;
                ls0 += plr[0]; ls1 += plr[1]; ls2 += plr[2]; ls3 += plr[3];
            }
            float inv[4] = {1.f / ls0, 1.f / ls1, 1.f / ls2, 1.f / ls3};
#pragma unroll
            for (int d = 0; d < 16; ++d) {
                float a = 0.f;
#pragma unroll
                for (int z = 0; z < 4; ++z)
                    a += P.paccp[((size_t)z * BN + row) * 16 + d];
                sa = fmaf(a * inv[d >> 2], P.pol_wo[d], sa);
            }
            float aa = (P.mask[row] == 0) ? NEGV : sa;
            local[i] = aa;
            mx = fmaxf(mx, aa);
        }
#pragma unroll
        for (int o = 32; o > 0; o >>= 1) mx = fmaxf(mx, __shfl_down(mx, o));
        if (lane == 0) wred[wid] = mx;
        __syncthreads();
        if (tid == 0) *sbc = fmaxf(fmaxf(wred[0], wred[1]), fmaxf(wred[2], wred[3]));
        __syncthreads();
        mx = *sbc;

        float s = 0.f;
#pragma unroll
        for (int i = 0; i < 4; ++i) {
            float p = __expf(local[i] - mx);
            local[i] = p;
            s += p;
        }
#pragma unroll
        for (int o = 32; o > 0; o >>= 1) s += __shfl_down(s, o);
        if (lane == 0) wred[wid] = s;
        __syncthreads();
        if (tid == 0) *sbc = wred[0] + wred[1] + wred[2] + wred[3];
        __syncthreads();
        float inv = 1.f / *sbc;
#pragma unroll
        for (int i = 0; i < 4; ++i) P.out_action[b * N + tid + i * 256] = local[i] * inv;
        __syncthreads();
    } else {
        int b = vb - B;
        float* cr  = (float*)smem;       // [1024]
        float* red = cr + 1024;          // [16][17]
#pragma unroll
        for (int i = 0; i < 4; ++i) {
            int idx = tid + i * 256;
            int row = b * N + idx;
            float sc = P.val_bo[0];
            float ls0 = 0.f, ls1 = 0.f, ls2 = 0.f, ls3 = 0.f;
#pragma unroll
            for (int z = 0; z < 4; ++z) {
                const float* plr = P.plv + ((size_t)z * BN + row) * 4;
                ls0 += plr[0]; ls1 += plr[1]; ls2 += plr[2]; ls3 += plr[3];
            }
            float inv[4] = {1.f / ls0, 1.f / ls1, 1.f / ls2, 1.f / ls3};
#pragma unroll
            for (int d = 0; d < 16; ++d) {
                float a = 0.f;
#pragma unroll
                for (int z = 0; z < 4; ++z)
                    a += P.paccv[((size_t)z * BN + row) * 16 + d];
                sc = fmaf(a * inv[d >> 2], P.val_wo[d], sc);
            }
            cr[idx] = sc;
        }
        __syncthreads();
        int c = tid & 15, seg = tid >> 4;
        float s = 0.f;
        int n0 = seg * 64;
        for (int n = n0; n < n0 + 64; ++n)
            s = fmaf(cr[n], P.v2_w[n * 16 + c], s);
        red[seg * 17 + c] = s;
        __syncthreads();
        if (tid < 16) {
            float acc = P.v2_b[tid];
#pragma unroll
            for (int g = 0; g < 16; ++g) acc += red[g * 17 + tid];
            P.out_critic[b * 16 + tid] = acc;
        }
        __syncthreads();
    }
}

// ---------------------------------------------------------------------------
// The mega-kernel: 7 phases separated by grid-wide syncs.
// ---------------------------------------------------------------------------
__global__ __launch_bounds__(256, 8) void mega_kernel(MP P) {
    cg::grid_group grid = cg::this_grid();
    __shared__ __align__(16) char smem[15616];

    // P1: qkv1 + prep
    for (int vb = blockIdx.x; vb < 9232; vb += gridDim.x) phase_qkv1_prep(P, vb);
    grid.sync();
    // P2: d1 attention (64 x 8 x 4 = 2048)
    for (int vb = blockIdx.x; vb < 2048; vb += gridDim.x)
        phase_attn<12>(P.q1h, P.k1h, P.v1h, P.q1h, P.k1h, P.v1h, P.mask,
                       P.pacc, P.plp, P.pacc, P.plp,
                       vb & 63, (vb >> 6) & 7, vb >> 9, smem);
    grid.sync();
    // P3: fold1 (1024)
    for (int vb = blockIdx.x; vb < 1024; vb += gridDim.x) phase_fold1(P, vb, smem);
    grid.sync();
    // P4: d2 attention (2048)
    for (int vb = blockIdx.x; vb < 2048; vb += gridDim.x)
        phase_attn<4>(P.q2h, P.k2h, P.v2h, P.q2h, P.k2h, P.v2h, P.mask,
                      P.pacc, P.plp, P.pacc, P.plp,
                      vb & 63, (vb >> 6) & 7, vb >> 9, smem);
    grid.sync();
    // P5: fold2 (2048)
    for (int vb = blockIdx.x; vb < 2048; vb += gridDim.x) phase_fold2(P, vb, smem);
    grid.sync();
    // P6: pol+val attention (128 x 8 x 4 = 4096)
    for (int vb = blockIdx.x; vb < 4096; vb += gridDim.x)
        phase_attn<4>(P.qph, P.kph, P.vph, P.qvh, P.kvh, P.vvh, P.mask,
                      P.paccp, P.plp, P.paccv, P.plv,
                      vb & 127, (vb >> 7) & 7, vb >> 10, smem);
    grid.sync();
    // P7: final (32)
    for (int vb = blockIdx.x; vb < 32; vb += gridDim.x) phase_final(P, vb, smem);
}

// ---------------------------------------------------------------------------
extern "C" void kernel_launch(void* const* d_in, const int* in_sizes, int n_in,
                              void* d_out, int out_size, void* d_ws, size_t ws_size,
                              hipStream_t stream) {
    const int B = 16, H = 4;
    const int N = 1024;
    const int BN = 16384;
    const int BHN = B * H * N;    // 65536
    const int KSPLIT = 4;

    MP p;
    p.r1       = (const float*)d_in[0];
    p.r2       = (const float*)d_in[1];
    p.edge     = (const float*)d_in[2];
    p.mask     = (const int*)d_in[3];
    p.d1_wqkv  = (const float*)d_in[4];
    p.d1_bqkv  = (const float*)d_in[5];
    p.d1_wo    = (const float*)d_in[6];
    p.d1_bo    = (const float*)d_in[7];
    p.d2_wqkv  = (const float*)d_in[8];
    p.d2_bqkv  = (const float*)d_in[9];
    p.d2_wo    = (const float*)d_in[10];
    p.d2_bo    = (const float*)d_in[11];
    p.pol_wqkv = (const float*)d_in[12];
    p.pol_bqkv = (const float*)d_in[13];
    p.pol_wo   = (const float*)d_in[14];
    p.pol_bo   = (const float*)d_in[15];
    p.val_wqkv = (const float*)d_in[16];
    p.val_bqkv = (const float*)d_in[17];
    p.val_wo   = (const float*)d_in[18];
    p.val_bo   = (const float*)d_in[19];
    p.v2_w     = (const float*)d_in[20];
    p.v2_b     = (const float*)d_in[21];

    float* ws = (float*)d_ws;
    p.pacc = ws;                                    // 4*BN*48
    p.plp  = p.pacc + 4 * BN * 48;                  // 4*BN*4
    p.plv  = p.plp + 4 * BN * 4;                    // 4*BN*4
    p.Wf1  = p.plv + 4 * BN * 4;                    // 2304
    p.bf1  = p.Wf1 + 2304;                          // 48
    p.Wfp  = p.bf1 + 48;                            // 768
    p.bfp  = p.Wfp + 768;                           // 48
    p.Wfv  = p.bfp + 48;                            // 768
    p.bfv  = p.Wfv + 768;                           // 48
    f16* fh = (f16*)(p.bfv + 48);
    p.q1h = fh;                                     // BHN*12
    p.k1h = p.q1h + (size_t)BHN * 12;
    p.v1h = p.k1h + (size_t)BHN * 12;
    p.q2h = p.v1h + (size_t)BHN * 12;               // BHN*4 each from here
    p.k2h = p.q2h + (size_t)BHN * 4;
    p.v2h = p.k2h + (size_t)BHN * 4;
    p.qph = p.v2h + (size_t)BHN * 4;
    p.kph = p.qph + (size_t)BHN * 4;
    p.vph = p.kph + (size_t)BHN * 4;
    p.qvh = p.vph + (size_t)BHN * 4;
    p.kvh = p.qvh + (size_t)BHN * 4;
    p.vvh = p.kvh + (size_t)BHN * 4;
    p.paccp = p.pacc;
    p.paccv = p.pacc + (size_t)KSPLIT * BN * 16;

    p.out_action = (float*)d_out;                   // B*N
    p.out_critic = p.out_action + BN;               // B*16

    p.qmul1 = (1.0f / sqrtf(12.0f)) * LOG2E;
    p.qmul2 = 0.5f * LOG2E;

    int maxB = 0;
    if (hipOccupancyMaxActiveBlocksPerMultiprocessor(&maxB, (const void*)mega_kernel, 256, 0)
            != hipSuccess || maxB <= 0)
        maxB = 4;
    long long nb = (long long)maxB * 256;           // 256 CUs on MI355X
    if (nb > 2048) nb = 2048;
    void* args[] = { (void*)&p };
    hipLaunchCooperativeKernel((const void*)mega_kernel, dim3((int)nb), dim3(256),
                               args, 0, stream);
}

// Round 16
// 607.705 us; speedup vs baseline: 1.6145x; 1.6145x over previous
//
#include <hip/hip_runtime.h>
#include <math.h>

#define NEGV (-1e9f)
#define LOG2E 1.4426950408889634f

typedef _Float16 f16;
typedef __attribute__((ext_vector_type(2))) __fp16 hf2;
typedef __attribute__((ext_vector_type(4))) _Float16 f16x4;
typedef __attribute__((ext_vector_type(4))) float f32x4;

// ---------------------------------------------------------------------------
// Launch 1: main blocks build f=[r1|r2|edge] -> d1 QKV (f16 head-major,
// Q pre-scaled). Tail 16 blocks fold affine pairs. Last tail block zeros the
// dependency counters (must happen every call; ws is not re-poisoned).
// ---------------------------------------------------------------------------
__global__ void qkv1_prep_kernel(
    const float* __restrict__ r1, const float* __restrict__ r2,
    const float* __restrict__ edge,
    const float* __restrict__ d1_wqkv, const float* __restrict__ d1_bqkv,
    const float* __restrict__ d1_wo, const float* __restrict__ d1_bo,
    const float* __restrict__ d2_wqkv, const float* __restrict__ d2_bqkv,
    const float* __restrict__ d2_wo, const float* __restrict__ d2_bo,
    const float* __restrict__ pol_wqkv, const float* __restrict__ pol_bqkv,
    const float* __restrict__ val_wqkv, const float* __restrict__ val_bqkv,
    f16* __restrict__ q1h, f16* __restrict__ k1h, f16* __restrict__ v1h,
    float* __restrict__ Wf1, float* __restrict__ bf1,
    float* __restrict__ Wfp, float* __restrict__ bfp,
    float* __restrict__ Wfv, float* __restrict__ bfv,
    int* __restrict__ cnts,
    int B, int M, int F, int H, float qmul1, int mainBlocks) {
    const int N = M * M;
    const int BN = B * N;

    if ((int)blockIdx.x < mainBlocks) {
        int t = blockIdx.x * blockDim.x + threadIdx.x;
        if (t >= 3 * BN * 48) return;
        int col = t % 48;
        int row = (t / 48) % BN;
        int mat = t / (48 * BN);
        int b = row / N, n = row % N;
        int i = n / M, j = n % M;

        const float* f1 = r1 + (b * M + i) * F;
        const float* f2 = r2 + (b * M + j) * F;
        const float* fe = edge + (size_t)row * F;
        const float* w  = d1_wqkv + mat * 48 * 48 + col;

        float s = d1_bqkv[mat * 48 + col];
#pragma unroll
        for (int d = 0; d < 16; ++d) s = fmaf(f1[d], w[d * 48], s);
#pragma unroll
        for (int d = 0; d < 16; ++d) s = fmaf(f2[d], w[(16 + d) * 48], s);
#pragma unroll
        for (int d = 0; d < 16; ++d) s = fmaf(fe[d], w[(32 + d) * 48], s);

        int h = col / 12, dd = col % 12;
        size_t off = ((size_t)(b * H + h) * N + n) * 12 + dd;
        if (mat == 0)      q1h[off] = (f16)(s * qmul1);
        else if (mat == 1) k1h[off] = (f16)s;
        else               v1h[off] = (f16)s;
        return;
    }

    if ((int)blockIdx.x == mainBlocks + 16) {      // counter-zero block
        if (threadIdx.x < 256) cnts[threadIdx.x] = 0;
        return;
    }

    // prep path (folded weights)
    int t = (blockIdx.x - mainBlocks) * 256 + threadIdx.x;
    if (t < 2304) {                     // Wf1
        int mat = t / 768, r = (t % 768) / 16, c = t % 16;
        float s = 0.f;
#pragma unroll
        for (int k = 0; k < 16; ++k)
            s = fmaf(d1_wo[r * 16 + k], d2_wqkv[mat * 256 + k * 16 + c], s);
        Wf1[t] = s;
        return;
    }
    int u = t - 2304;
    if (u < 48) {                       // bf1
        int mat = u / 16, c = u % 16;
        float s = d2_bqkv[mat * 16 + c];
#pragma unroll
        for (int k = 0; k < 16; ++k)
            s = fmaf(d1_bo[k], d2_wqkv[mat * 256 + k * 16 + c], s);
        bf1[u] = s;
        return;
    }
    u -= 48;
    if (u < 768) {                      // Wfp
        int mat = u / 256, r = (u % 256) / 16, c = u % 16;
        float s = 0.f;
#pragma unroll
        for (int k = 0; k < 16; ++k)
            s = fmaf(d2_wo[r * 16 + k], pol_wqkv[mat * 256 + k * 16 + c], s);
        Wfp[u] = s;
        return;
    }
    u -= 768;
    if (u < 48) {                       // bfp
        int mat = u / 16, c = u % 16;
        float s = pol_bqkv[mat * 16 + c];
#pragma unroll
        for (int k = 0; k < 16; ++k)
            s = fmaf(d2_bo[k], pol_wqkv[mat * 256 + k * 16 + c], s);
        bfp[u] = s;
        return;
    }
    u -= 48;
    if (u < 768) {                      // Wfv
        int mat = u / 256, r = (u % 256) / 16, c = u % 16;
        float s = 0.f;
#pragma unroll
        for (int k = 0; k < 16; ++k)
            s = fmaf(d2_wo[r * 16 + k], val_wqkv[mat * 256 + k * 16 + c], s);
        Wfv[u] = s;
        return;
    }
    u -= 768;
    if (u < 48) {                       // bfv
        int mat = u / 16, c = u % 16;
        float s = val_bqkv[mat * 16 + c];
#pragma unroll
        for (int k = 0; k < 16; ++k)
            s = fmaf(d2_bo[k], val_wqkv[mat * 256 + k * 16 + c], s);
        bfv[u] = s;
    }
}

// ---------------------------------------------------------------------------
// Attention body (R14 logic): LDS-staged, f16 head-major inputs, QT=2.
// Writes partial (pacc, pl). smem arena provided by caller.
// ---------------------------------------------------------------------------
template <int DH>
__device__ void attn_body(const f16* __restrict__ qh, const f16* __restrict__ kh,
                          const f16* __restrict__ vh, const int* __restrict__ mask,
                          float* __restrict__ pacc, float* __restrict__ pl,
                          int bhs, int by, int bz, char* smem, int B, int H, int N) {
    const int LD = H * DH;
    int b = bhs / H, h = bhs % H;
    int kbase = bz * 256;
    int bN = b * N;

    f16 (*Kt)[DH]  = (f16(*)[DH])smem;                       // [256][DH]
    f16 (*Vt)[264] = (f16(*)[264])(smem + 256 * DH * 2);     // [16][264]
    float* mbs     = (float*)(smem + 256 * DH * 2 + 16 * 264 * 2);

    int tid = threadIdx.x;
    {
        int kk = tid;
        const f16* kB = kh + ((size_t)bhs * N + kbase) * DH;
        const f16* vB = vh + ((size_t)bhs * N + kbase) * DH;
#pragma unroll
        for (int d = 0; d < DH / 4; ++d)
            ((uint2*)&Kt[kk][0])[d] = ((const uint2*)(kB + (size_t)kk * DH))[d];
        uint2 vr[DH / 4];
#pragma unroll
        for (int d = 0; d < DH / 4; ++d)
            vr[d] = ((const uint2*)(vB + (size_t)kk * DH))[d];
        const f16* vv = (const f16*)vr;
#pragma unroll
        for (int d = 0; d < DH; ++d) Vt[d][kk] = vv[d];
        Vt[DH][kk] = (f16)1.f;
        mbs[kk] = mask[bN + kbase + kk] ? (-8.f * LOG2E) : NEGV;
    }
    __syncthreads();

    int lane = tid & 63, wid = tid >> 6;
    int lrow = lane & 15, lg = lane >> 4;
    int qbase = by * 128 + wid * 32;

    const f16* qB = qh + (size_t)bhs * N * DH;
    f16x4 zf = {(f16)0.f, (f16)0.f, (f16)0.f, (f16)0.f};
    bool qok = (4 * lg < DH);
    f16x4 qf[2];
#pragma unroll
    for (int qt = 0; qt < 2; ++qt)
        qf[qt] = qok ? *(const f16x4*)(qB + (size_t)(qbase + qt * 16 + lrow) * DH + 4 * lg) : zf;

    f32x4 oacc[2];
#pragma unroll
    for (int qt = 0; qt < 2; ++qt) oacc[qt] = (f32x4){0.f, 0.f, 0.f, 0.f};

#pragma unroll 8
    for (int t16 = 0; t16 < 16; ++t16) {
        f16x4 kf = *(const f16x4*)(&Kt[0][0] + (size_t)(t16 * 16 + lrow) * DH + 4 * lg);
        float4 mv = *(const float4*)(&mbs[t16 * 16 + 4 * lg]);
        f32x4 mc = {mv.x, mv.y, mv.z, mv.w};
        f16x4 vb = *(const f16x4*)(&Vt[lrow][t16 * 16 + 4 * lg]);

#pragma unroll
        for (int qt = 0; qt < 2; ++qt) {
            f32x4 s = __builtin_amdgcn_mfma_f32_16x16x16f16(kf, qf[qt], mc, 0, 0, 0);
            hf2 lo = __builtin_amdgcn_cvt_pkrtz(__builtin_amdgcn_exp2f(s[0]),
                                                __builtin_amdgcn_exp2f(s[1]));
            hf2 hi = __builtin_amdgcn_cvt_pkrtz(__builtin_amdgcn_exp2f(s[2]),
                                                __builtin_amdgcn_exp2f(s[3]));
            f16x4 pa;
            ((hf2*)&pa)[0] = lo;
            ((hf2*)&pa)[1] = hi;
            oacc[qt] = __builtin_amdgcn_mfma_f32_16x16x16f16(pa, vb, oacc[qt], 0, 0, 0);
        }
    }

    int d = lrow;
    size_t zoff = (size_t)bz * B * N;
#pragma unroll
    for (int qt = 0; qt < 2; ++qt) {
#pragma unroll
        for (int r = 0; r < 4; ++r) {
            int q = qbase + qt * 16 + lg * 4 + r;
            float val = oacc[qt][r];
            if (d < DH)
                pacc[(zoff + bN + q) * LD + h * DH + d] = val;
            else if (d == DH)
                pl[(zoff + bN + q) * H + h] = val;
        }
    }
}

// ---------------------------------------------------------------------------
// Launch 2: d1 attention + (last block of each (b,qy) cell) fold1.
// Cell = 16 blocks (4 heads x 4 k-chunks). Winner folds its 128 rows.
// ---------------------------------------------------------------------------
__global__ __launch_bounds__(256, 8) void attn1_fold1_kernel(
    const f16* __restrict__ qh, const f16* __restrict__ kh, const f16* __restrict__ vh,
    const int* __restrict__ mask,
    float* __restrict__ pacc, float* __restrict__ pl,
    const float* __restrict__ Wf1, const float* __restrict__ bf1,
    f16* __restrict__ q2h, f16* __restrict__ k2h, f16* __restrict__ v2h,
    int* __restrict__ cnts,
    int B, int H, int N, float qmul2) {
    const int BN = B * N;
    __shared__ __align__(16) char smem[15616];
    __shared__ int win;

    int bx = blockIdx.x, by = blockIdx.y, bz = blockIdx.z;
    attn_body<12>(qh, kh, vh, mask, pacc, pl, bx, by, bz, smem, B, H, N);
    __syncthreads();

    int b = bx / H;
    int cell = b * 8 + by;
    if (threadIdx.x == 0) {
        int old = __hip_atomic_fetch_add(&cnts[cell], 1, __ATOMIC_ACQ_REL,
                                         __HIP_MEMORY_SCOPE_AGENT);
        win = (old == 15);
    }
    __syncthreads();
    if (!win) return;

    // fold1 for rows [b*N + by*128, +128)
    float* comb = (float*)smem;          // [16][49]
    float* invl = comb + 16 * 49;        // [16][4]
    int tid = threadIdx.x;
    for (int g = 0; g < 8; ++g) {
        int row0 = b * N + by * 128 + g * 16;
        if (tid < 64) {
            int r = tid >> 2, h = tid & 3;
            float ls = 0.f;
#pragma unroll
            for (int z = 0; z < 4; ++z) ls += pl[((size_t)z * BN + row0 + r) * 4 + h];
            invl[r * 4 + h] = 1.f / ls;
        }
        __syncthreads();
#pragma unroll
        for (int k = 0; k < 3; ++k) {
            int idx = tid + k * 256;
            int r = idx / 48, d = idx % 48;
            float a = 0.f;
#pragma unroll
            for (int z = 0; z < 4; ++z) a += pacc[((size_t)z * BN + row0 + r) * 48 + d];
            comb[r * 49 + d] = a * invl[r * 4 + d / 12];
        }
        __syncthreads();
#pragma unroll
        for (int k = 0; k < 3; ++k) {
            int idx = tid + k * 256;
            int mat = idx / 256, r = (idx % 256) / 16, c = idx % 16;
            float s = bf1[mat * 16 + c];
            const float* wcol = Wf1 + mat * 768 + c;
#pragma unroll
            for (int d = 0; d < 48; ++d)
                s = fmaf(comb[r * 49 + d], wcol[d * 16], s);
            int row = row0 + r;
            int bb = row / N, n = row % N;
            int h = c >> 2, dd = c & 3;
            size_t off = ((size_t)(bb * H + h) * N + n) * 4 + dd;
            if (mat == 0)      q2h[off] = (f16)(s * qmul2);
            else if (mat == 1) k2h[off] = (f16)s;
            else               v2h[off] = (f16)s;
        }
        __syncthreads();
    }
}

// ---------------------------------------------------------------------------
// Launch 3: d2 attention + (winner) fold2 -> pol/val QKV.
// ---------------------------------------------------------------------------
__global__ __launch_bounds__(256, 8) void attn2_fold2_kernel(
    const f16* __restrict__ qh, const f16* __restrict__ kh, const f16* __restrict__ vh,
    const int* __restrict__ mask,
    float* __restrict__ pacc, float* __restrict__ pl,
    const float* __restrict__ Wfp, const float* __restrict__ bfp,
    const float* __restrict__ Wfv, const float* __restrict__ bfv,
    f16* __restrict__ qph, f16* __restrict__ kph, f16* __restrict__ vph,
    f16* __restrict__ qvh, f16* __restrict__ kvh, f16* __restrict__ vvh,
    int* __restrict__ cnts,
    int B, int H, int N, float qmul2) {
    const int BN = B * N;
    __shared__ __align__(16) char smem[11520];
    __shared__ int win;

    int bx = blockIdx.x, by = blockIdx.y, bz = blockIdx.z;
    attn_body<4>(qh, kh, vh, mask, pacc, pl, bx, by, bz, smem, B, H, N);
    __syncthreads();

    int b = bx / H;
    int cell = b * 8 + by;
    if (threadIdx.x == 0) {
        int old = __hip_atomic_fetch_add(&cnts[cell], 1, __ATOMIC_ACQ_REL,
                                         __HIP_MEMORY_SCOPE_AGENT);
        win = (old == 15);
    }
    __syncthreads();
    if (!win) return;

    // fold2 for rows [b*N + by*128, +128), 16 groups of 8 rows
    float* comb = (float*)smem;          // [8][17]
    float* invl = comb + 8 * 17;         // [8][4]
    int tid = threadIdx.x;
    for (int g = 0; g < 16; ++g) {
        int row0 = b * N + by * 128 + g * 8;
        if (tid < 32) {
            int r = tid >> 2, h = tid & 3;
            float ls = 0.f;
#pragma unroll
            for (int z = 0; z < 4; ++z) ls += pl[((size_t)z * BN + row0 + r) * 4 + h];
            invl[r * 4 + h] = 1.f / ls;
        }
        __syncthreads();
        if (tid < 128) {
            int r = tid / 16, d = tid % 16;
            float a = 0.f;
#pragma unroll
            for (int z = 0; z < 4; ++z) a += pacc[((size_t)z * BN + row0 + r) * 16 + d];
            comb[r * 17 + d] = a * invl[r * 4 + (d >> 2)];
        }
        __syncthreads();
#pragma unroll
        for (int k = 0; k < 3; ++k) {
            int idx = tid + k * 256;
            int set = idx / 384;
            int rem = idx % 384;
            int mat = rem / 128, r = (rem % 128) / 16, c = rem % 16;
            const float* W  = set ? Wfv : Wfp;
            const float* bb = set ? bfv : bfp;
            float s = bb[mat * 16 + c];
            const float* wcol = W + mat * 256 + c;
#pragma unroll
            for (int d = 0; d < 16; ++d)
                s = fmaf(comb[r * 17 + d], wcol[d * 16], s);
            int row = row0 + r;
            int bb2 = row / N, n = row % N;
            int h = c >> 2, dd = c & 3;
            size_t off = ((size_t)(bb2 * H + h) * N + n) * 4 + dd;
            f16* dst;
            if (set == 0) dst = (mat == 0) ? qph : (mat == 1) ? kph : vph;
            else          dst = (mat == 0) ? qvh : (mat == 1) ? kvh : vvh;
            dst[off] = (f16)((mat == 0) ? s * qmul2 : s);
        }
        __syncthreads();
    }
}

// ---------------------------------------------------------------------------
// Launch 4: pol + val attention (two sets in one launch), R14 kernel.
// ---------------------------------------------------------------------------
template <int DH, int QT>
__global__ __launch_bounds__(256, 8) void attn_h_kernel(
    const f16* __restrict__ qh1, const f16* __restrict__ kh1, const f16* __restrict__ vh1,
    const f16* __restrict__ qh2, const f16* __restrict__ kh2, const f16* __restrict__ vh2,
    const int* __restrict__ mask,
    float* __restrict__ pacc1, float* __restrict__ pl1,
    float* __restrict__ pacc2, float* __restrict__ pl2,
    int B, int H, int N) {
    const int BH = B * H;
    __shared__ __align__(16) char smem[11520];
    int bhs = blockIdx.x;
    const f16* qh; const f16* kh; const f16* vh;
    float* pacc; float* pl;
    if (bhs < BH) { qh = qh1; kh = kh1; vh = vh1; pacc = pacc1; pl = pl1; }
    else          { qh = qh2; kh = kh2; vh = vh2; pacc = pacc2; pl = pl2; bhs -= BH; }
    attn_body<DH>(qh, kh, vh, mask, pacc, pl, bhs, blockIdx.y, blockIdx.z, smem, B, H, N);
}

// ---------------------------------------------------------------------------
// Launch 5: heads + masked softmax + critic (R14 final2).
// ---------------------------------------------------------------------------
__global__ __launch_bounds__(256) void final2_kernel(
    const float* __restrict__ paccp, const float* __restrict__ plp,
    const float* __restrict__ paccv, const float* __restrict__ plv,
    const float* __restrict__ pol_wo, const float* __restrict__ pol_bo,
    const float* __restrict__ val_wo, const float* __restrict__ val_bo,
    const int* __restrict__ mask, const float* __restrict__ v2w,
    const float* __restrict__ v2b,
    float* __restrict__ out_action, float* __restrict__ out_critic,
    int N, int B, int BN) {
    int tid = threadIdx.x;
    if ((int)blockIdx.x < B) {
        int b = blockIdx.x;
        int lane = tid & 63, wid = tid >> 6;
        __shared__ float wred[4];
        __shared__ float sbcast;

        float local[4];
        float mx = -INFINITY;
#pragma unroll
        for (int i = 0; i < 4; ++i) {
            int row = b * N + tid + i * 256;
            float sa = pol_bo[0];
            float ls0 = 0.f, ls1 = 0.f, ls2 = 0.f, ls3 = 0.f;
#pragma unroll
            for (int z = 0; z < 4; ++z) {
                const float* plr = plp + ((size_t)z * BN + row) * 4;
                ls0 += plr[0]; ls1 += plr[1]; ls2 += plr[2]; ls3 += plr[3];
            }
            float inv[4] = {1.f / ls0, 1.f / ls1, 1.f / ls2, 1.f / ls3};
#pragma unroll
            for (int d = 0; d < 16; ++d) {
                float a = 0.f;
#pragma unroll
                for (int z = 0; z < 4; ++z)
                    a += paccp[((size_t)z * BN + row) * 16 + d];
                sa = fmaf(a * inv[d >> 2], pol_wo[d], sa);
            }
            float aa = (mask[row] == 0) ? NEGV : sa;
            local[i] = aa;
            mx = fmaxf(mx, aa);
        }
#pragma unroll
        for (int o = 32; o > 0; o >>= 1) mx = fmaxf(mx, __shfl_down(mx, o));
        if (lane == 0) wred[wid] = mx;
        __syncthreads();
        if (tid == 0) sbcast = fmaxf(fmaxf(wred[0], wred[1]), fmaxf(wred[2], wred[3]));
        __syncthreads();
        mx = sbcast;

        float s = 0.f;
#pragma unroll
        for (int i = 0; i < 4; ++i) {
            float p = __expf(local[i] - mx);
            local[i] = p;
            s += p;
        }
#pragma unroll
        for (int o = 32; o > 0; o >>= 1) s += __shfl_down(s, o);
        if (lane == 0) wred[wid] = s;
        __syncthreads();
        if (tid == 0) sbcast = wred[0] + wred[1] + wred[2] + wred[3];
        __syncthreads();
        float inv = 1.f / sbcast;
#pragma unroll
        for (int i = 0; i < 4; ++i) out_action[b * N + tid + i * 256] = local[i] * inv;
    } else {
        int b = blockIdx.x - B;
        __shared__ float cr[1024];
        __shared__ float red[16][17];
#pragma unroll
        for (int i = 0; i < 4; ++i) {
            int idx = tid + i * 256;
            int row = b * N + idx;
            float sc = val_bo[0];
            float ls0 = 0.f, ls1 = 0.f, ls2 = 0.f, ls3 = 0.f;
#pragma unroll
            for (int z = 0; z < 4; ++z) {
                const float* plr = plv + ((size_t)z * BN + row) * 4;
                ls0 += plr[0]; ls1 += plr[1]; ls2 += plr[2]; ls3 += plr[3];
            }
            float inv[4] = {1.f / ls0, 1.f / ls1, 1.f / ls2, 1.f / ls3};
#pragma unroll
            for (int d = 0; d < 16; ++d) {
                float a = 0.f;
#pragma unroll
                for (int z = 0; z < 4; ++z)
                    a += paccv[((size_t)z * BN + row) * 16 + d];
                sc = fmaf(a * inv[d >> 2], val_wo[d], sc);
            }
            cr[idx] = sc;
        }
        __syncthreads();
        int c = tid & 15, seg = tid >> 4;
        float s = 0.f;
        int n0 = seg * 64;
        for (int n = n0; n < n0 + 64; ++n)
            s = fmaf(cr[n], v2w[n * 16 + c], s);
        red[seg][c] = s;
        __syncthreads();
        if (tid < 16) {
            float acc = v2b[tid];
#pragma unroll
            for (int g = 0; g < 16; ++g) acc += red[g][tid];
            out_critic[b * 16 + tid] = acc;
        }
    }
}

// ---------------------------------------------------------------------------
extern "C" void kernel_launch(void* const* d_in, const int* in_sizes, int n_in,
                              void* d_out, int out_size, void* d_ws, size_t ws_size,
                              hipStream_t stream) {
    const int B = 16, M = 32, F = 16, H = 4;
    const int N = M * M;          // 1024
    const int BN = B * N;         // 16384
    const int BHN = B * H * N;    // 65536
    const int KSPLIT = 4;

    const float* r1       = (const float*)d_in[0];
    const float* r2       = (const float*)d_in[1];
    const float* edge     = (const float*)d_in[2];
    const int*   mask     = (const int*)d_in[3];
    const float* d1_wqkv  = (const float*)d_in[4];
    const float* d1_bqkv  = (const float*)d_in[5];
    const float* d1_wo    = (const float*)d_in[6];
    const float* d1_bo    = (const float*)d_in[7];
    const float* d2_wqkv  = (const float*)d_in[8];
    const float* d2_bqkv  = (const float*)d_in[9];
    const float* d2_wo    = (const float*)d_in[10];
    const float* d2_bo    = (const float*)d_in[11];
    const float* pol_wqkv = (const float*)d_in[12];
    const float* pol_bqkv = (const float*)d_in[13];
    const float* pol_wo   = (const float*)d_in[14];
    const float* pol_bo   = (const float*)d_in[15];
    const float* val_wqkv = (const float*)d_in[16];
    const float* val_bqkv = (const float*)d_in[17];
    const float* val_wo   = (const float*)d_in[18];
    const float* val_bo   = (const float*)d_in[19];
    const float* v2_w     = (const float*)d_in[20];
    const float* v2_b     = (const float*)d_in[21];

    float* ws = (float*)d_ws;
    float* pacc = ws;                               // 4*BN*48
    float* plp  = pacc + 4 * BN * 48;               // 4*BN*4
    float* plv  = plp + 4 * BN * 4;                 // 4*BN*4
    float* Wf1  = plv + 4 * BN * 4;                 // 2304
    float* bf1  = Wf1 + 2304;                       // 48
    float* Wfp  = bf1 + 48;                         // 768
    float* bfp  = Wfp + 768;                        // 48
    float* Wfv  = bfp + 48;                         // 768
    float* bfv  = Wfv + 768;                        // 48
    int*   cnts = (int*)(bfv + 48);                 // 256 ints (128 + 128)
    f16* fh  = (f16*)(cnts + 256);
    f16* q1h = fh;                                  // BHN*12
    f16* k1h = q1h + (size_t)BHN * 12;
    f16* v1h = k1h + (size_t)BHN * 12;
    f16* q2h = v1h + (size_t)BHN * 12;              // BHN*4 each from here
    f16* k2h = q2h + (size_t)BHN * 4;
    f16* v2h = k2h + (size_t)BHN * 4;
    f16* qph = v2h + (size_t)BHN * 4;
    f16* kph = qph + (size_t)BHN * 4;
    f16* vph = kph + (size_t)BHN * 4;
    f16* qvh = vph + (size_t)BHN * 4;
    f16* kvh = qvh + (size_t)BHN * 4;
    f16* vvh = kvh + (size_t)BHN * 4;
    float* paccp = pacc;
    float* paccv = pacc + (size_t)KSPLIT * BN * 16;

    float* out_action = (float*)d_out;              // B*N
    float* out_critic = out_action + BN;            // B*16

    const float qmul1 = (1.0f / sqrtf(12.0f)) * LOG2E;
    const float qmul2 = 0.5f * LOG2E;

    // 1. d1 QKV + folded weights + counter zeroing
    {
        int mainBlocks = (3 * BN * 48 + 255) / 256;
        qkv1_prep_kernel<<<mainBlocks + 17, 256, 0, stream>>>(
            r1, r2, edge, d1_wqkv, d1_bqkv, d1_wo, d1_bo,
            d2_wqkv, d2_bqkv, d2_wo, d2_bo,
            pol_wqkv, pol_bqkv, val_wqkv, val_bqkv,
            q1h, k1h, v1h, Wf1, bf1, Wfp, bfp, Wfv, bfv, cnts,
            B, M, F, H, qmul1, mainBlocks);
    }
    // 2. d1 attention + fold1 (winner-block)
    attn1_fold1_kernel<<<dim3(B * H, N / 128, KSPLIT), 256, 0, stream>>>(
        q1h, k1h, v1h, mask, pacc, plp, Wf1, bf1, q2h, k2h, v2h,
        cnts, B, H, N, qmul2);
    // 3. d2 attention + fold2 (winner-block)
    attn2_fold2_kernel<<<dim3(B * H, N / 128, KSPLIT), 256, 0, stream>>>(
        q2h, k2h, v2h, mask, pacc, plp, Wfp, bfp, Wfv, bfv,
        qph, kph, vph, qvh, kvh, vvh, cnts + 128, B, H, N, qmul2);
    // 4. pol + val attention (two sets)
    attn_h_kernel<4, 2><<<dim3(2 * B * H, N / 128, KSPLIT), 256, 0, stream>>>(
        qph, kph, vph, qvh, kvh, vvh, mask,
        paccp, plp, paccv, plv, B, H, N);
    // 5. heads + masked softmax + critic
    final2_kernel<<<2 * B, 256, 0, stream>>>(
        paccp, plp, paccv, plv, pol_wo, pol_bo, val_wo, val_bo,
        mask, v2_w, v2_b, out_action, out_critic, N, B, BN);
}

// Round 17
// 107.336 us; speedup vs baseline: 9.1408x; 5.6617x over previous
//
#include <hip/hip_runtime.h>
#include <math.h>

#define NEGV (-1e9f)
#define LOG2E 1.4426950408889634f

typedef _Float16 f16;
typedef __attribute__((ext_vector_type(2))) __fp16 hf2;
typedef __attribute__((ext_vector_type(4))) _Float16 f16x4;
typedef __attribute__((ext_vector_type(4))) float f32x4;

// ---------------------------------------------------------------------------
// Launch 1: main blocks build f=[r1|r2|edge] -> d1 QKV (f16 head-major,
// Q pre-scaled). Tail 16 blocks fold the affine pairs.
// ---------------------------------------------------------------------------
__global__ void qkv1_prep_kernel(
    const float* __restrict__ r1, const float* __restrict__ r2,
    const float* __restrict__ edge,
    const float* __restrict__ d1_wqkv, const float* __restrict__ d1_bqkv,
    const float* __restrict__ d1_wo, const float* __restrict__ d1_bo,
    const float* __restrict__ d2_wqkv, const float* __restrict__ d2_bqkv,
    const float* __restrict__ d2_wo, const float* __restrict__ d2_bo,
    const float* __restrict__ pol_wqkv, const float* __restrict__ pol_bqkv,
    const float* __restrict__ val_wqkv, const float* __restrict__ val_bqkv,
    f16* __restrict__ q1h, f16* __restrict__ k1h, f16* __restrict__ v1h,
    float* __restrict__ Wf1, float* __restrict__ bf1,
    float* __restrict__ Wfp, float* __restrict__ bfp,
    float* __restrict__ Wfv, float* __restrict__ bfv,
    int B, int M, int F, int H, float qmul1, int mainBlocks) {
    const int N = M * M;
    const int BN = B * N;

    if ((int)blockIdx.x < mainBlocks) {
        int t = blockIdx.x * blockDim.x + threadIdx.x;
        if (t >= 3 * BN * 48) return;
        int col = t % 48;
        int row = (t / 48) % BN;
        int mat = t / (48 * BN);
        int b = row / N, n = row % N;
        int i = n / M, j = n % M;

        const float* f1 = r1 + (b * M + i) * F;
        const float* f2 = r2 + (b * M + j) * F;
        const float* fe = edge + (size_t)row * F;
        const float* w  = d1_wqkv + mat * 48 * 48 + col;

        float s = d1_bqkv[mat * 48 + col];
#pragma unroll
        for (int d = 0; d < 16; ++d) s = fmaf(f1[d], w[d * 48], s);
#pragma unroll
        for (int d = 0; d < 16; ++d) s = fmaf(f2[d], w[(16 + d) * 48], s);
#pragma unroll
        for (int d = 0; d < 16; ++d) s = fmaf(fe[d], w[(32 + d) * 48], s);

        int h = col / 12, dd = col % 12;
        size_t off = ((size_t)(b * H + h) * N + n) * 12 + dd;
        if (mat == 0)      q1h[off] = (f16)(s * qmul1);
        else if (mat == 1) k1h[off] = (f16)s;
        else               v1h[off] = (f16)s;
        return;
    }

    // prep path (folded weights)
    int t = (blockIdx.x - mainBlocks) * 256 + threadIdx.x;
    if (t < 2304) {                     // Wf1
        int mat = t / 768, r = (t % 768) / 16, c = t % 16;
        float s = 0.f;
#pragma unroll
        for (int k = 0; k < 16; ++k)
            s = fmaf(d1_wo[r * 16 + k], d2_wqkv[mat * 256 + k * 16 + c], s);
        Wf1[t] = s;
        return;
    }
    int u = t - 2304;
    if (u < 48) {                       // bf1
        int mat = u / 16, c = u % 16;
        float s = d2_bqkv[mat * 16 + c];
#pragma unroll
        for (int k = 0; k < 16; ++k)
            s = fmaf(d1_bo[k], d2_wqkv[mat * 256 + k * 16 + c], s);
        bf1[u] = s;
        return;
    }
    u -= 48;
    if (u < 768) {                      // Wfp
        int mat = u / 256, r = (u % 256) / 16, c = u % 16;
        float s = 0.f;
#pragma unroll
        for (int k = 0; k < 16; ++k)
            s = fmaf(d2_wo[r * 16 + k], pol_wqkv[mat * 256 + k * 16 + c], s);
        Wfp[u] = s;
        return;
    }
    u -= 768;
    if (u < 48) {                       // bfp
        int mat = u / 16, c = u % 16;
        float s = pol_bqkv[mat * 16 + c];
#pragma unroll
        for (int k = 0; k < 16; ++k)
            s = fmaf(d2_bo[k], pol_wqkv[mat * 256 + k * 16 + c], s);
        bfp[u] = s;
        return;
    }
    u -= 48;
    if (u < 768) {                      // Wfv
        int mat = u / 256, r = (u % 256) / 16, c = u % 16;
        float s = 0.f;
#pragma unroll
        for (int k = 0; k < 16; ++k)
            s = fmaf(d2_wo[r * 16 + k], val_wqkv[mat * 256 + k * 16 + c], s);
        Wfv[u] = s;
        return;
    }
    u -= 768;
    if (u < 48) {                       // bfv
        int mat = u / 16, c = u % 16;
        float s = val_bqkv[mat * 16 + c];
#pragma unroll
        for (int k = 0; k < 16; ++k)
            s = fmaf(d2_bo[k], val_wqkv[mat * 256 + k * 16 + c], s);
        bfv[u] = s;
    }
}

// ---------------------------------------------------------------------------
// Full-N attention core: block = 512 threads (8 waves); wave w handles head
// (w&3), q-subtile (w>>2). Block covers 32 q-rows x all 4 heads of batch b,
// looping over all 4 key-chunks (no-max softmax -> plain accumulation).
// Output: comb[32][combStride] = normalized attended rows (all heads concat).
// LDS arena layout: [Kt: 4*256*DH f16 | Vt: VROWS*264 f16 | mbs: 256 f32].
// Vt per head = DH+1 rows (V^T + ones); rows read past DH are garbage and
// discarded; K over-read past DH nullified by zero-padded Q.
// ---------------------------------------------------------------------------
template <int DH>
__device__ inline void attn_core(const f16* __restrict__ qh, const f16* __restrict__ kh,
                                 const f16* __restrict__ vh, const int* __restrict__ mask,
                                 int b, int qg, int H, int N,
                                 f16* __restrict__ Kt, f16* __restrict__ Vt,
                                 float* __restrict__ mbs,
                                 float* __restrict__ comb, int combStride) {
    int tid = threadIdx.x;
    int wave = tid >> 6, lane = tid & 63;
    int h = wave & 3, qhalf = wave >> 2;
    int lrow = lane & 15, lg = lane >> 4;
    int bhs = b * H + h;
    int qrow = qg * 32 + qhalf * 16 + lrow;

    f16x4 zf = {(f16)0.f, (f16)0.f, (f16)0.f, (f16)0.f};
    bool qok = (4 * lg < DH);
    f16x4 qf = qok ? *(const f16x4*)(qh + ((size_t)bhs * N + qrow) * DH + 4 * lg) : zf;

    f32x4 oacc = {0.f, 0.f, 0.f, 0.f};

    for (int chunk = 0; chunk < 4; ++chunk) {
        int kbase = chunk * 256;
        __syncthreads();
        for (int idx = tid; idx < 1024; idx += 512) {
            int hh = idx >> 8, kk = idx & 255;
            const f16* kB = kh + ((size_t)(b * H + hh) * N + kbase + kk) * DH;
            const f16* vB = vh + ((size_t)(b * H + hh) * N + kbase + kk) * DH;
#pragma unroll
            for (int d4 = 0; d4 < DH / 4; ++d4)
                ((uint2*)(Kt + ((size_t)hh * 256 + kk) * DH))[d4] = ((const uint2*)kB)[d4];
            uint2 vr[DH / 4];
#pragma unroll
            for (int d4 = 0; d4 < DH / 4; ++d4) vr[d4] = ((const uint2*)vB)[d4];
            const f16* vv = (const f16*)vr;
#pragma unroll
            for (int d = 0; d < DH; ++d)
                Vt[(hh * (DH + 1) + d) * 264 + kk] = vv[d];
            Vt[(hh * (DH + 1) + DH) * 264 + kk] = (f16)1.f;
        }
        if (tid < 256) mbs[tid] = mask[b * N + kbase + tid] ? (-8.f * LOG2E) : NEGV;
        __syncthreads();

        const f16* KtH = Kt + (size_t)h * 256 * DH;
        const f16* VtH = Vt + (size_t)h * (DH + 1) * 264;
#pragma unroll 8
        for (int t16 = 0; t16 < 16; ++t16) {
            f16x4 kf = *(const f16x4*)(KtH + (size_t)(t16 * 16 + lrow) * DH + 4 * lg);
            float4 mv = *(const float4*)(mbs + t16 * 16 + 4 * lg);
            f32x4 mc = {mv.x, mv.y, mv.z, mv.w};
            f16x4 vb = *(const f16x4*)(VtH + (size_t)lrow * 264 + t16 * 16 + 4 * lg);

            f32x4 s = __builtin_amdgcn_mfma_f32_16x16x16f16(kf, qf, mc, 0, 0, 0);
            hf2 lo = __builtin_amdgcn_cvt_pkrtz(__builtin_amdgcn_exp2f(s[0]),
                                                __builtin_amdgcn_exp2f(s[1]));
            hf2 hi = __builtin_amdgcn_cvt_pkrtz(__builtin_amdgcn_exp2f(s[2]),
                                                __builtin_amdgcn_exp2f(s[3]));
            f16x4 pa;
            ((hf2*)&pa)[0] = lo;
            ((hf2*)&pa)[1] = hi;
            oacc = __builtin_amdgcn_mfma_f32_16x16x16f16(pa, vb, oacc, 0, 0, 0);
        }
    }

    __syncthreads();   // all LDS reads done; comb may overlay Kt
    // O layout: q-row (in wave tile) = 4*lg + r, output dim = lrow; l at lrow==DH
#pragma unroll
    for (int r = 0; r < 4; ++r) {
        float lr = __shfl(oacc[r], (lane & 48) | DH);
        if (lrow < DH)
            comb[(qhalf * 16 + lg * 4 + r) * combStride + h * DH + lrow] = oacc[r] / lr;
    }
    __syncthreads();
}

// ---------------------------------------------------------------------------
// Launch 2: d1 attention (full-N, all heads) + in-block fold1 -> d2 QKV.
// grid (32, 16): x = qg, y = b.
// ---------------------------------------------------------------------------
__global__ __launch_bounds__(512, 4) void attn1_fold1_kernel(
    const f16* __restrict__ q1h, const f16* __restrict__ k1h, const f16* __restrict__ v1h,
    const int* __restrict__ mask,
    const float* __restrict__ Wf1, const float* __restrict__ bf1,
    f16* __restrict__ q2h, f16* __restrict__ k2h, f16* __restrict__ v2h,
    int H, int N, float qmul2) {
    const int DH = 12;
    const int VROWS = 3 * (DH + 1) + 16;           // 55
    __shared__ __align__(16) f16 KtA[4 * 256 * DH];
    __shared__ __align__(16) f16 VtA[VROWS * 264];
    __shared__ __align__(16) float mbsA[256];

    int qg = blockIdx.x, b = blockIdx.y;
    float* comb = (float*)KtA;                     // [32][49] overlay
    attn_core<DH>(q1h, k1h, v1h, mask, b, qg, H, N, KtA, VtA, mbsA, comb, 49);

    int tid = threadIdx.x;
#pragma unroll
    for (int k = 0; k < 3; ++k) {                  // 1536 outputs
        int idx = tid + k * 512;
        int mat = idx / 512, r = (idx % 512) / 16, c = idx % 16;
        float s = bf1[mat * 16 + c];
        const float* wcol = Wf1 + mat * 768 + c;
#pragma unroll
        for (int d = 0; d < 48; ++d)
            s = fmaf(comb[r * 49 + d], wcol[d * 16], s);
        int n = qg * 32 + r;
        int hh = c >> 2, dd = c & 3;
        size_t off = ((size_t)(b * H + hh) * N + n) * 4 + dd;
        if (mat == 0)      q2h[off] = (f16)(s * qmul2);
        else if (mat == 1) k2h[off] = (f16)s;
        else               v2h[off] = (f16)s;
    }
}

// ---------------------------------------------------------------------------
// Launch 3: d2 attention (full-N) + in-block fold2 -> pol/val QKV.
// grid (32, 16): x = qg, y = b.
// ---------------------------------------------------------------------------
__global__ __launch_bounds__(512, 8) void attn2_fold2_kernel(
    const f16* __restrict__ q2h, const f16* __restrict__ k2h, const f16* __restrict__ v2h,
    const int* __restrict__ mask,
    const float* __restrict__ Wfp, const float* __restrict__ bfp,
    const float* __restrict__ Wfv, const float* __restrict__ bfv,
    f16* __restrict__ qph, f16* __restrict__ kph, f16* __restrict__ vph,
    f16* __restrict__ qvh, f16* __restrict__ kvh, f16* __restrict__ vvh,
    int H, int N, float qmul2) {
    const int DH = 4;
    const int VROWS = 3 * (DH + 1) + 16;           // 31
    __shared__ __align__(16) f16 KtA[4 * 256 * DH];
    __shared__ __align__(16) f16 VtA[VROWS * 264];
    __shared__ __align__(16) float mbsA[256];

    int qg = blockIdx.x, b = blockIdx.y;
    float* comb = (float*)KtA;                     // [32][17] overlay
    attn_core<DH>(q2h, k2h, v2h, mask, b, qg, H, N, KtA, VtA, mbsA, comb, 17);

    int tid = threadIdx.x;
#pragma unroll
    for (int k = 0; k < 6; ++k) {                  // 3072 outputs
        int idx = tid + k * 512;
        int set = idx / 1536;
        int rem = idx % 1536;
        int mat = rem / 512, r = (rem % 512) / 16, c = rem % 16;
        const float* W  = set ? Wfv : Wfp;
        const float* bb = set ? bfv : bfp;
        float s = bb[mat * 16 + c];
        const float* wcol = W + mat * 256 + c;
#pragma unroll
        for (int d = 0; d < 16; ++d)
            s = fmaf(comb[r * 17 + d], wcol[d * 16], s);
        int n = qg * 32 + r;
        int hh = c >> 2, dd = c & 3;
        size_t off = ((size_t)(b * H + hh) * N + n) * 4 + dd;
        f16* dst;
        if (set == 0) dst = (mat == 0) ? qph : (mat == 1) ? kph : vph;
        else          dst = (mat == 0) ? qvh : (mat == 1) ? kvh : vvh;
        dst[off] = (f16)((mat == 0) ? s * qmul2 : s);
    }
}

// ---------------------------------------------------------------------------
// Launch 4: pol/val attention (full-N) + in-block head projection 16->1.
// grid (32, 16, 2): x = qg, y = b, z = set (0 pol -> araw, 1 val -> craw).
// ---------------------------------------------------------------------------
__global__ __launch_bounds__(512, 8) void attn3_heads_kernel(
    const f16* __restrict__ qph, const f16* __restrict__ kph, const f16* __restrict__ vph,
    const f16* __restrict__ qvh, const f16* __restrict__ kvh, const f16* __restrict__ vvh,
    const int* __restrict__ mask,
    const float* __restrict__ pol_wo, const float* __restrict__ pol_bo,
    const float* __restrict__ val_wo, const float* __restrict__ val_bo,
    float* __restrict__ araw, float* __restrict__ craw,
    int H, int N) {
    const int DH = 4;
    const int VROWS = 3 * (DH + 1) + 16;
    __shared__ __align__(16) f16 KtA[4 * 256 * DH];
    __shared__ __align__(16) f16 VtA[VROWS * 264];
    __shared__ __align__(16) float mbsA[256];

    int qg = blockIdx.x, b = blockIdx.y, set = blockIdx.z;
    const f16* qh = set ? qvh : qph;
    const f16* kh = set ? kvh : kph;
    const f16* vh = set ? vvh : vph;
    float* comb = (float*)KtA;                     // [32][17] overlay
    attn_core<DH>(qh, kh, vh, mask, b, qg, H, N, KtA, VtA, mbsA, comb, 17);

    int tid = threadIdx.x;
    if (tid < 32) {
        int r = tid;
        const float* wo = set ? val_wo : pol_wo;
        float s = (set ? val_bo : pol_bo)[0];
#pragma unroll
        for (int d = 0; d < 16; ++d) s = fmaf(comb[r * 17 + d], wo[d], s);
        (set ? craw : araw)[b * N + qg * 32 + r] = s;
    }
}

// ---------------------------------------------------------------------------
// Launch 5: blocks 0..B-1 masked action softmax; blocks B..2B-1 critic matvec.
// ---------------------------------------------------------------------------
__global__ __launch_bounds__(256) void final_kernel(
    const float* __restrict__ araw, const int* __restrict__ mask,
    const float* __restrict__ craw, const float* __restrict__ v2w,
    const float* __restrict__ v2b,
    float* __restrict__ out_action, float* __restrict__ out_critic, int N, int B) {
    int tid = threadIdx.x;
    if ((int)blockIdx.x < B) {
        int b = blockIdx.x;
        int lane = tid & 63, wid = tid >> 6;
        __shared__ float wred[4];
        __shared__ float sbcast;

        float local[4];
        float mx = -INFINITY;
#pragma unroll
        for (int i = 0; i < 4; ++i) {
            int n = tid + i * 256;
            float a = araw[b * N + n];
            if (mask[b * N + n] == 0) a = NEGV;
            local[i] = a;
            mx = fmaxf(mx, a);
        }
#pragma unroll
        for (int o = 32; o > 0; o >>= 1) mx = fmaxf(mx, __shfl_down(mx, o));
        if (lane == 0) wred[wid] = mx;
        __syncthreads();
        if (tid == 0) sbcast = fmaxf(fmaxf(wred[0], wred[1]), fmaxf(wred[2], wred[3]));
        __syncthreads();
        mx = sbcast;

        float s = 0.f;
#pragma unroll
        for (int i = 0; i < 4; ++i) {
            float p = __expf(local[i] - mx);
            local[i] = p;
            s += p;
        }
#pragma unroll
        for (int o = 32; o > 0; o >>= 1) s += __shfl_down(s, o);
        if (lane == 0) wred[wid] = s;
        __syncthreads();
        if (tid == 0) sbcast = wred[0] + wred[1] + wred[2] + wred[3];
        __syncthreads();
        float inv = 1.f / sbcast;
#pragma unroll
        for (int i = 0; i < 4; ++i) out_action[b * N + tid + i * 256] = local[i] * inv;
    } else {
        int b = blockIdx.x - B;
        int c = tid & 15, seg = tid >> 4;
        __shared__ float red[16][17];
        float s = 0.f;
        int n0 = seg * 64;
        for (int n = n0; n < n0 + 64; ++n)
            s = fmaf(craw[b * N + n], v2w[n * 16 + c], s);
        red[seg][c] = s;
        __syncthreads();
        if (tid < 16) {
            float acc = v2b[tid];
#pragma unroll
            for (int g = 0; g < 16; ++g) acc += red[g][tid];
            out_critic[b * 16 + tid] = acc;
        }
    }
}

// ---------------------------------------------------------------------------
extern "C" void kernel_launch(void* const* d_in, const int* in_sizes, int n_in,
                              void* d_out, int out_size, void* d_ws, size_t ws_size,
                              hipStream_t stream) {
    const int B = 16, M = 32, F = 16, H = 4;
    const int N = M * M;          // 1024
    const int BN = B * N;         // 16384
    const int BHN = B * H * N;    // 65536

    const float* r1       = (const float*)d_in[0];
    const float* r2       = (const float*)d_in[1];
    const float* edge     = (const float*)d_in[2];
    const int*   mask     = (const int*)d_in[3];
    const float* d1_wqkv  = (const float*)d_in[4];
    const float* d1_bqkv  = (const float*)d_in[5];
    const float* d1_wo    = (const float*)d_in[6];
    const float* d1_bo    = (const float*)d_in[7];
    const float* d2_wqkv  = (const float*)d_in[8];
    const float* d2_bqkv  = (const float*)d_in[9];
    const float* d2_wo    = (const float*)d_in[10];
    const float* d2_bo    = (const float*)d_in[11];
    const float* pol_wqkv = (const float*)d_in[12];
    const float* pol_bqkv = (const float*)d_in[13];
    const float* pol_wo   = (const float*)d_in[14];
    const float* pol_bo   = (const float*)d_in[15];
    const float* val_wqkv = (const float*)d_in[16];
    const float* val_bqkv = (const float*)d_in[17];
    const float* val_wo   = (const float*)d_in[18];
    const float* val_bo   = (const float*)d_in[19];
    const float* v2_w     = (const float*)d_in[20];
    const float* v2_b     = (const float*)d_in[21];

    float* ws = (float*)d_ws;
    float* Wf1  = ws;                               // 2304
    float* bf1  = Wf1 + 2304;                       // 48
    float* Wfp  = bf1 + 48;                         // 768
    float* bfp  = Wfp + 768;                        // 48
    float* Wfv  = bfp + 48;                         // 768
    float* bfv  = Wfv + 768;                        // 48
    float* araw = bfv + 48;                         // BN
    float* craw = araw + BN;                        // BN
    f16* fh  = (f16*)(craw + BN);
    f16* q1h = fh;                                  // BHN*12
    f16* k1h = q1h + (size_t)BHN * 12;
    f16* v1h = k1h + (size_t)BHN * 12;
    f16* q2h = v1h + (size_t)BHN * 12;              // BHN*4 each from here
    f16* k2h = q2h + (size_t)BHN * 4;
    f16* v2h = k2h + (size_t)BHN * 4;
    f16* qph = v2h + (size_t)BHN * 4;
    f16* kph = qph + (size_t)BHN * 4;
    f16* vph = kph + (size_t)BHN * 4;
    f16* qvh = vph + (size_t)BHN * 4;
    f16* kvh = qvh + (size_t)BHN * 4;
    f16* vvh = kvh + (size_t)BHN * 4;

    float* out_action = (float*)d_out;              // B*N
    float* out_critic = out_action + BN;            // B*16

    const float qmul1 = (1.0f / sqrtf(12.0f)) * LOG2E;
    const float qmul2 = 0.5f * LOG2E;

    // 1. d1 QKV (f16 head-major) + folded weights
    {
        int mainBlocks = (3 * BN * 48 + 255) / 256;   // 9216
        qkv1_prep_kernel<<<mainBlocks + 16, 256, 0, stream>>>(
            r1, r2, edge, d1_wqkv, d1_bqkv, d1_wo, d1_bo,
            d2_wqkv, d2_bqkv, d2_wo, d2_bo,
            pol_wqkv, pol_bqkv, val_wqkv, val_bqkv,
            q1h, k1h, v1h, Wf1, bf1, Wfp, bfp, Wfv, bfv,
            B, M, F, H, qmul1, mainBlocks);
    }
    // 2. d1 attention + fold1 -> d2 QKV
    attn1_fold1_kernel<<<dim3(N / 32, B), 512, 0, stream>>>(
        q1h, k1h, v1h, mask, Wf1, bf1, q2h, k2h, v2h, H, N, qmul2);
    // 3. d2 attention + fold2 -> pol/val QKV
    attn2_fold2_kernel<<<dim3(N / 32, B), 512, 0, stream>>>(
        q2h, k2h, v2h, mask, Wfp, bfp, Wfv, bfv,
        qph, kph, vph, qvh, kvh, vvh, H, N, qmul2);
    // 4. pol/val attention + head projections -> araw/craw
    attn3_heads_kernel<<<dim3(N / 32, B, 2), 512, 0, stream>>>(
        qph, kph, vph, qvh, kvh, vvh, mask,
        pol_wo, pol_bo, val_wo, val_bo, araw, craw, H, N);
    // 5. masked softmax + critic
    final_kernel<<<2 * B, 256, 0, stream>>>(
        araw, mask, craw, v2_w, v2_b, out_action, out_critic, N, B);
}

// Round 18
// 97.762 us; speedup vs baseline: 10.0360x; 1.0979x over previous
//
#include <hip/hip_runtime.h>
#include <math.h>

#define NEGV (-1e9f)
#define LOG2E 1.4426950408889634f

typedef _Float16 f16;
typedef __attribute__((ext_vector_type(2))) __fp16 hf2;
typedef __attribute__((ext_vector_type(4))) _Float16 f16x4;
typedef __attribute__((ext_vector_type(4))) float f32x4;

// ---------------------------------------------------------------------------
// Launch 1: blocks 0..255: MFMA d1-QKV. Block = 64 f-rows x all 144 outputs
// (3 mats x 48). F tile (64x48 f16, built from r1|r2|edge) and W^T (144x48
// f16) staged in LDS with stride 50 (odd -> conflict-free frag reads).
// C = mfma(A=F, B=W^T) + bias via C operand. Outputs written f16 head-major
// [BH][N][12], Q pre-scaled by qmul1.
// Blocks 256..271: fold the affine pairs (Wf1/bf1, Wfp/bfp, Wfv/bfv).
// ---------------------------------------------------------------------------
__global__ __launch_bounds__(256, 4) void qkv1_mfma_prep_kernel(
    const float* __restrict__ r1, const float* __restrict__ r2,
    const float* __restrict__ edge,
    const float* __restrict__ d1_wqkv, const float* __restrict__ d1_bqkv,
    const float* __restrict__ d1_wo, const float* __restrict__ d1_bo,
    const float* __restrict__ d2_wqkv, const float* __restrict__ d2_bqkv,
    const float* __restrict__ d2_wo, const float* __restrict__ d2_bo,
    const float* __restrict__ pol_wqkv, const float* __restrict__ pol_bqkv,
    const float* __restrict__ val_wqkv, const float* __restrict__ val_bqkv,
    f16* __restrict__ q1h, f16* __restrict__ k1h, f16* __restrict__ v1h,
    float* __restrict__ Wf1, float* __restrict__ bf1,
    float* __restrict__ Wfp, float* __restrict__ bfp,
    float* __restrict__ Wfv, float* __restrict__ bfv,
    float qmul1) {
    const int N = 1024, M = 32, H = 4;

    if ((int)blockIdx.x < 256) {
        __shared__ __align__(16) f16 Ft[64 * 50];
        __shared__ __align__(16) f16 Wt[144 * 50];
        int tid = threadIdx.x;
        int row0 = blockIdx.x * 64;
        int b = row0 / N;                       // constant per block (64 | N)

        // stage F = [r1_bcast | r2_bcast | edge] rows, f16
        for (int idx = tid; idx < 64 * 48; idx += 256) {
            int rr = idx / 48, c = idx % 48;
            int n = (row0 + rr) % N;
            int i = n / M, j = n % M;
            float v;
            if (c < 16)      v = r1[(b * M + i) * 16 + c];
            else if (c < 32) v = r2[(b * M + j) * 16 + (c - 16)];
            else             v = edge[(size_t)(row0 + rr) * 16 + (c - 32)];
            Ft[rr * 50 + c] = (f16)v;
        }
        // stage W^T: Wt[(mat*48+c)*50 + k] = wqkv[mat][k][c]
        for (int idx = tid; idx < 6912; idx += 256) {
            int mat = idx / 2304, rem = idx % 2304;
            int k = rem / 48, c = rem % 48;
            Wt[(mat * 48 + c) * 50 + k] = (f16)d1_wqkv[mat * 2304 + k * 48 + c];
        }
        __syncthreads();

        int lane = tid & 63, wave = tid >> 6;
        int lrow = lane & 15, lg = lane >> 4;

        // A-frags: F rows (row = wave*16 + lrow), 3 k-tiles (K=48)
        const f16* Frow = Ft + (wave * 16 + lrow) * 50;
        f16x4 af[3];
#pragma unroll
        for (int kt = 0; kt < 3; ++kt)
            af[kt] = *(const f16x4*)(Frow + kt * 16 + 4 * lg);

#pragma unroll
        for (int ct = 0; ct < 9; ++ct) {
            int gcol = ct * 16 + lrow;
            int mat = gcol / 48, c48 = gcol % 48;
            float bias = d1_bqkv[mat * 48 + c48];
            f32x4 acc = {bias, bias, bias, bias};
            const f16* Wcol = Wt + gcol * 50;
#pragma unroll
            for (int kt = 0; kt < 3; ++kt) {
                f16x4 bf = *(const f16x4*)(Wcol + kt * 16 + 4 * lg);
                acc = __builtin_amdgcn_mfma_f32_16x16x16f16(af[kt], bf, acc, 0, 0, 0);
            }
            int h = c48 / 12, dd = c48 % 12;
            f16* dst = (mat == 0) ? q1h : (mat == 1) ? k1h : v1h;
            float mul = (mat == 0) ? qmul1 : 1.f;
#pragma unroll
            for (int r = 0; r < 4; ++r) {
                int n = (row0 + wave * 16 + 4 * lg + r) % N;
                dst[((size_t)(b * H + h) * N + n) * 12 + dd] = (f16)(acc[r] * mul);
            }
        }
        return;
    }

    // prep path (folded weights)
    int t = (blockIdx.x - 256) * 256 + threadIdx.x;
    if (t < 2304) {                     // Wf1
        int mat = t / 768, r = (t % 768) / 16, c = t % 16;
        float s = 0.f;
#pragma unroll
        for (int k = 0; k < 16; ++k)
            s = fmaf(d1_wo[r * 16 + k], d2_wqkv[mat * 256 + k * 16 + c], s);
        Wf1[t] = s;
        return;
    }
    int u = t - 2304;
    if (u < 48) {                       // bf1
        int mat = u / 16, c = u % 16;
        float s = d2_bqkv[mat * 16 + c];
#pragma unroll
        for (int k = 0; k < 16; ++k)
            s = fmaf(d1_bo[k], d2_wqkv[mat * 256 + k * 16 + c], s);
        bf1[u] = s;
        return;
    }
    u -= 48;
    if (u < 768) {                      // Wfp
        int mat = u / 256, r = (u % 256) / 16, c = u % 16;
        float s = 0.f;
#pragma unroll
        for (int k = 0; k < 16; ++k)
            s = fmaf(d2_wo[r * 16 + k], pol_wqkv[mat * 256 + k * 16 + c], s);
        Wfp[u] = s;
        return;
    }
    u -= 768;
    if (u < 48) {                       // bfp
        int mat = u / 16, c = u % 16;
        float s = pol_bqkv[mat * 16 + c];
#pragma unroll
        for (int k = 0; k < 16; ++k)
            s = fmaf(d2_bo[k], pol_wqkv[mat * 256 + k * 16 + c], s);
        bfp[u] = s;
        return;
    }
    u -= 48;
    if (u < 768) {                      // Wfv
        int mat = u / 256, r = (u % 256) / 16, c = u % 16;
        float s = 0.f;
#pragma unroll
        for (int k = 0; k < 16; ++k)
            s = fmaf(d2_wo[r * 16 + k], val_wqkv[mat * 256 + k * 16 + c], s);
        Wfv[u] = s;
        return;
    }
    u -= 768;
    if (u < 48) {                       // bfv
        int mat = u / 16, c = u % 16;
        float s = val_bqkv[mat * 16 + c];
#pragma unroll
        for (int k = 0; k < 16; ++k)
            s = fmaf(d2_bo[k], val_wqkv[mat * 256 + k * 16 + c], s);
        bfv[u] = s;
    }
}

// ---------------------------------------------------------------------------
// Full-N attention core: block = 512 threads (8 waves); wave w handles head
// (w&3), q-subtile (w>>2). Block covers 32 q-rows x all 4 heads of batch b,
// looping over all 4 key-chunks (no-max softmax -> plain accumulation).
// Output: comb[32][combStride] = normalized attended rows (all heads concat).
// ---------------------------------------------------------------------------
template <int DH>
__device__ inline void attn_core(const f16* __restrict__ qh, const f16* __restrict__ kh,
                                 const f16* __restrict__ vh, const int* __restrict__ mask,
                                 int b, int qg, int H, int N,
                                 f16* __restrict__ Kt, f16* __restrict__ Vt,
                                 float* __restrict__ mbs,
                                 float* __restrict__ comb, int combStride) {
    int tid = threadIdx.x;
    int wave = tid >> 6, lane = tid & 63;
    int h = wave & 3, qhalf = wave >> 2;
    int lrow = lane & 15, lg = lane >> 4;
    int bhs = b * H + h;
    int qrow = qg * 32 + qhalf * 16 + lrow;

    f16x4 zf = {(f16)0.f, (f16)0.f, (f16)0.f, (f16)0.f};
    bool qok = (4 * lg < DH);
    f16x4 qf = qok ? *(const f16x4*)(qh + ((size_t)bhs * N + qrow) * DH + 4 * lg) : zf;

    f32x4 oacc = {0.f, 0.f, 0.f, 0.f};

    for (int chunk = 0; chunk < 4; ++chunk) {
        int kbase = chunk * 256;
        __syncthreads();
        for (int idx = tid; idx < 1024; idx += 512) {
            int hh = idx >> 8, kk = idx & 255;
            const f16* kB = kh + ((size_t)(b * H + hh) * N + kbase + kk) * DH;
            const f16* vB = vh + ((size_t)(b * H + hh) * N + kbase + kk) * DH;
#pragma unroll
            for (int d4 = 0; d4 < DH / 4; ++d4)
                ((uint2*)(Kt + ((size_t)hh * 256 + kk) * DH))[d4] = ((const uint2*)kB)[d4];
            uint2 vr[DH / 4];
#pragma unroll
            for (int d4 = 0; d4 < DH / 4; ++d4) vr[d4] = ((const uint2*)vB)[d4];
            const f16* vv = (const f16*)vr;
#pragma unroll
            for (int d = 0; d < DH; ++d)
                Vt[(hh * (DH + 1) + d) * 264 + kk] = vv[d];
            Vt[(hh * (DH + 1) + DH) * 264 + kk] = (f16)1.f;
        }
        if (tid < 256) mbs[tid] = mask[b * N + kbase + tid] ? (-8.f * LOG2E) : NEGV;
        __syncthreads();

        const f16* KtH = Kt + (size_t)h * 256 * DH;
        const f16* VtH = Vt + (size_t)h * (DH + 1) * 264;
#pragma unroll 8
        for (int t16 = 0; t16 < 16; ++t16) {
            f16x4 kf = *(const f16x4*)(KtH + (size_t)(t16 * 16 + lrow) * DH + 4 * lg);
            float4 mv = *(const float4*)(mbs + t16 * 16 + 4 * lg);
            f32x4 mc = {mv.x, mv.y, mv.z, mv.w};
            f16x4 vb = *(const f16x4*)(VtH + (size_t)lrow * 264 + t16 * 16 + 4 * lg);

            f32x4 s = __builtin_amdgcn_mfma_f32_16x16x16f16(kf, qf, mc, 0, 0, 0);
            hf2 lo = __builtin_amdgcn_cvt_pkrtz(__builtin_amdgcn_exp2f(s[0]),
                                                __builtin_amdgcn_exp2f(s[1]));
            hf2 hi = __builtin_amdgcn_cvt_pkrtz(__builtin_amdgcn_exp2f(s[2]),
                                                __builtin_amdgcn_exp2f(s[3]));
            f16x4 pa;
            ((hf2*)&pa)[0] = lo;
            ((hf2*)&pa)[1] = hi;
            oacc = __builtin_amdgcn_mfma_f32_16x16x16f16(pa, vb, oacc, 0, 0, 0);
        }
    }

    __syncthreads();   // all LDS reads done; comb may overlay Kt
#pragma unroll
    for (int r = 0; r < 4; ++r) {
        float lr = __shfl(oacc[r], (lane & 48) | DH);
        if (lrow < DH)
            comb[(qhalf * 16 + lg * 4 + r) * combStride + h * DH + lrow] = oacc[r] / lr;
    }
    __syncthreads();
}

// ---------------------------------------------------------------------------
// Launch 2: d1 attention (full-N, all heads) + in-block fold1 -> d2 QKV.
// ---------------------------------------------------------------------------
__global__ __launch_bounds__(512, 4) void attn1_fold1_kernel(
    const f16* __restrict__ q1h, const f16* __restrict__ k1h, const f16* __restrict__ v1h,
    const int* __restrict__ mask,
    const float* __restrict__ Wf1, const float* __restrict__ bf1,
    f16* __restrict__ q2h, f16* __restrict__ k2h, f16* __restrict__ v2h,
    int H, int N, float qmul2) {
    const int DH = 12;
    const int VROWS = 3 * (DH + 1) + 16;           // 55
    __shared__ __align__(16) f16 KtA[4 * 256 * DH];
    __shared__ __align__(16) f16 VtA[VROWS * 264];
    __shared__ __align__(16) float mbsA[256];

    int qg = blockIdx.x, b = blockIdx.y;
    float* comb = (float*)KtA;                     // [32][49] overlay
    attn_core<DH>(q1h, k1h, v1h, mask, b, qg, H, N, KtA, VtA, mbsA, comb, 49);

    int tid = threadIdx.x;
#pragma unroll
    for (int k = 0; k < 3; ++k) {                  // 1536 outputs
        int idx = tid + k * 512;
        int mat = idx / 512, r = (idx % 512) / 16, c = idx % 16;
        float s = bf1[mat * 16 + c];
        const float* wcol = Wf1 + mat * 768 + c;
#pragma unroll
        for (int d = 0; d < 48; ++d)
            s = fmaf(comb[r * 49 + d], wcol[d * 16], s);
        int n = qg * 32 + r;
        int hh = c >> 2, dd = c & 3;
        size_t off = ((size_t)(b * H + hh) * N + n) * 4 + dd;
        if (mat == 0)      q2h[off] = (f16)(s * qmul2);
        else if (mat == 1) k2h[off] = (f16)s;
        else               v2h[off] = (f16)s;
    }
}

// ---------------------------------------------------------------------------
// Launch 3: d2 attention (full-N) + in-block fold2 -> pol/val QKV.
// ---------------------------------------------------------------------------
__global__ __launch_bounds__(512, 8) void attn2_fold2_kernel(
    const f16* __restrict__ q2h, const f16* __restrict__ k2h, const f16* __restrict__ v2h,
    const int* __restrict__ mask,
    const float* __restrict__ Wfp, const float* __restrict__ bfp,
    const float* __restrict__ Wfv, const float* __restrict__ bfv,
    f16* __restrict__ qph, f16* __restrict__ kph, f16* __restrict__ vph,
    f16* __restrict__ qvh, f16* __restrict__ kvh, f16* __restrict__ vvh,
    int H, int N, float qmul2) {
    const int DH = 4;
    const int VROWS = 3 * (DH + 1) + 16;           // 31
    __shared__ __align__(16) f16 KtA[4 * 256 * DH];
    __shared__ __align__(16) f16 VtA[VROWS * 264];
    __shared__ __align__(16) float mbsA[256];

    int qg = blockIdx.x, b = blockIdx.y;
    float* comb = (float*)KtA;                     // [32][17] overlay
    attn_core<DH>(q2h, k2h, v2h, mask, b, qg, H, N, KtA, VtA, mbsA, comb, 17);

    int tid = threadIdx.x;
#pragma unroll
    for (int k = 0; k < 6; ++k) {                  // 3072 outputs
        int idx = tid + k * 512;
        int set = idx / 1536;
        int rem = idx % 1536;
        int mat = rem / 512, r = (rem % 512) / 16, c = rem % 16;
        const float* W  = set ? Wfv : Wfp;
        const float* bb = set ? bfv : bfp;
        float s = bb[mat * 16 + c];
        const float* wcol = W + mat * 256 + c;
#pragma unroll
        for (int d = 0; d < 16; ++d)
            s = fmaf(comb[r * 17 + d], wcol[d * 16], s);
        int n = qg * 32 + r;
        int hh = c >> 2, dd = c & 3;
        size_t off = ((size_t)(b * H + hh) * N + n) * 4 + dd;
        f16* dst;
        if (set == 0) dst = (mat == 0) ? qph : (mat == 1) ? kph : vph;
        else          dst = (mat == 0) ? qvh : (mat == 1) ? kvh : vvh;
        dst[off] = (f16)((mat == 0) ? s * qmul2 : s);
    }
}

// ---------------------------------------------------------------------------
// Launch 4: pol/val attention (full-N) + in-block head projection 16->1.
// ---------------------------------------------------------------------------
__global__ __launch_bounds__(512, 8) void attn3_heads_kernel(
    const f16* __restrict__ qph, const f16* __restrict__ kph, const f16* __restrict__ vph,
    const f16* __restrict__ qvh, const f16* __restrict__ kvh, const f16* __restrict__ vvh,
    const int* __restrict__ mask,
    const float* __restrict__ pol_wo, const float* __restrict__ pol_bo,
    const float* __restrict__ val_wo, const float* __restrict__ val_bo,
    float* __restrict__ araw, float* __restrict__ craw,
    int H, int N) {
    const int DH = 4;
    const int VROWS = 3 * (DH + 1) + 16;
    __shared__ __align__(16) f16 KtA[4 * 256 * DH];
    __shared__ __align__(16) f16 VtA[VROWS * 264];
    __shared__ __align__(16) float mbsA[256];

    int qg = blockIdx.x, b = blockIdx.y, set = blockIdx.z;
    const f16* qh = set ? qvh : qph;
    const f16* kh = set ? kvh : kph;
    const f16* vh = set ? vvh : vph;
    float* comb = (float*)KtA;                     // [32][17] overlay
    attn_core<DH>(qh, kh, vh, mask, b, qg, H, N, KtA, VtA, mbsA, comb, 17);

    int tid = threadIdx.x;
    if (tid < 32) {
        int r = tid;
        const float* wo = set ? val_wo : pol_wo;
        float s = (set ? val_bo : pol_bo)[0];
#pragma unroll
        for (int d = 0; d < 16; ++d) s = fmaf(comb[r * 17 + d], wo[d], s);
        (set ? craw : araw)[b * N + qg * 32 + r] = s;
    }
}

// ---------------------------------------------------------------------------
// Launch 5: blocks 0..B-1 masked action softmax; blocks B..2B-1 critic matvec.
// ---------------------------------------------------------------------------
__global__ __launch_bounds__(256) void final_kernel(
    const float* __restrict__ araw, const int* __restrict__ mask,
    const float* __restrict__ craw, const float* __restrict__ v2w,
    const float* __restrict__ v2b,
    float* __restrict__ out_action, float* __restrict__ out_critic, int N, int B) {
    int tid = threadIdx.x;
    if ((int)blockIdx.x < B) {
        int b = blockIdx.x;
        int lane = tid & 63, wid = tid >> 6;
        __shared__ float wred[4];
        __shared__ float sbcast;

        float local[4];
        float mx = -INFINITY;
#pragma unroll
        for (int i = 0; i < 4; ++i) {
            int n = tid + i * 256;
            float a = araw[b * N + n];
            if (mask[b * N + n] == 0) a = NEGV;
            local[i] = a;
            mx = fmaxf(mx, a);
        }
#pragma unroll
        for (int o = 32; o > 0; o >>= 1) mx = fmaxf(mx, __shfl_down(mx, o));
        if (lane == 0) wred[wid] = mx;
        __syncthreads();
        if (tid == 0) sbcast = fmaxf(fmaxf(wred[0], wred[1]), fmaxf(wred[2], wred[3]));
        __syncthreads();
        mx = sbcast;

        float s = 0.f;
#pragma unroll
        for (int i = 0; i < 4; ++i) {
            float p = __expf(local[i] - mx);
            local[i] = p;
            s += p;
        }
#pragma unroll
        for (int o = 32; o > 0; o >>= 1) s += __shfl_down(s, o);
        if (lane == 0) wred[wid] = s;
        __syncthreads();
        if (tid == 0) sbcast = wred[0] + wred[1] + wred[2] + wred[3];
        __syncthreads();
        float inv = 1.f / sbcast;
#pragma unroll
        for (int i = 0; i < 4; ++i) out_action[b * N + tid + i * 256] = local[i] * inv;
    } else {
        int b = blockIdx.x - B;
        int c = tid & 15, seg = tid >> 4;
        __shared__ float red[16][17];
        float s = 0.f;
        int n0 = seg * 64;
        for (int n = n0; n < n0 + 64; ++n)
            s = fmaf(craw[b * N + n], v2w[n * 16 + c], s);
        red[seg][c] = s;
        __syncthreads();
        if (tid < 16) {
            float acc = v2b[tid];
#pragma unroll
            for (int g = 0; g < 16; ++g) acc += red[g][tid];
            out_critic[b * 16 + tid] = acc;
        }
    }
}

// ---------------------------------------------------------------------------
extern "C" void kernel_launch(void* const* d_in, const int* in_sizes, int n_in,
                              void* d_out, int out_size, void* d_ws, size_t ws_size,
                              hipStream_t stream) {
    const int B = 16, M = 32, F = 16, H = 4;
    const int N = M * M;          // 1024
    const int BN = B * N;         // 16384
    const int BHN = B * H * N;    // 65536

    const float* r1       = (const float*)d_in[0];
    const float* r2       = (const float*)d_in[1];
    const float* edge     = (const float*)d_in[2];
    const int*   mask     = (const int*)d_in[3];
    const float* d1_wqkv  = (const float*)d_in[4];
    const float* d1_bqkv  = (const float*)d_in[5];
    const float* d1_wo    = (const float*)d_in[6];
    const float* d1_bo    = (const float*)d_in[7];
    const float* d2_wqkv  = (const float*)d_in[8];
    const float* d2_bqkv  = (const float*)d_in[9];
    const float* d2_wo    = (const float*)d_in[10];
    const float* d2_bo    = (const float*)d_in[11];
    const float* pol_wqkv = (const float*)d_in[12];
    const float* pol_bqkv = (const float*)d_in[13];
    const float* pol_wo   = (const float*)d_in[14];
    const float* pol_bo   = (const float*)d_in[15];
    const float* val_wqkv = (const float*)d_in[16];
    const float* val_bqkv = (const float*)d_in[17];
    const float* val_wo   = (const float*)d_in[18];
    const float* val_bo   = (const float*)d_in[19];
    const float* v2_w     = (const float*)d_in[20];
    const float* v2_b     = (const float*)d_in[21];

    float* ws = (float*)d_ws;
    float* Wf1  = ws;                               // 2304
    float* bf1  = Wf1 + 2304;                       // 48
    float* Wfp  = bf1 + 48;                         // 768
    float* bfp  = Wfp + 768;                        // 48
    float* Wfv  = bfp + 48;                         // 768
    float* bfv  = Wfv + 768;                        // 48
    float* araw = bfv + 48;                         // BN
    float* craw = araw + BN;                        // BN
    f16* fh  = (f16*)(craw + BN);
    f16* q1h = fh;                                  // BHN*12
    f16* k1h = q1h + (size_t)BHN * 12;
    f16* v1h = k1h + (size_t)BHN * 12;
    f16* q2h = v1h + (size_t)BHN * 12;              // BHN*4 each from here
    f16* k2h = q2h + (size_t)BHN * 4;
    f16* v2h = k2h + (size_t)BHN * 4;
    f16* qph = v2h + (size_t)BHN * 4;
    f16* kph = qph + (size_t)BHN * 4;
    f16* vph = kph + (size_t)BHN * 4;
    f16* qvh = vph + (size_t)BHN * 4;
    f16* kvh = qvh + (size_t)BHN * 4;
    f16* vvh = kvh + (size_t)BHN * 4;

    float* out_action = (float*)d_out;              // B*N
    float* out_critic = out_action + BN;            // B*16

    const float qmul1 = (1.0f / sqrtf(12.0f)) * LOG2E;
    const float qmul2 = 0.5f * LOG2E;

    // 1. d1 QKV via MFMA (f16 head-major) + folded weights
    qkv1_mfma_prep_kernel<<<256 + 16, 256, 0, stream>>>(
        r1, r2, edge, d1_wqkv, d1_bqkv, d1_wo, d1_bo,
        d2_wqkv, d2_bqkv, d2_wo, d2_bo,
        pol_wqkv, pol_bqkv, val_wqkv, val_bqkv,
        q1h, k1h, v1h, Wf1, bf1, Wfp, bfp, Wfv, bfv, qmul1);
    // 2. d1 attention + fold1 -> d2 QKV
    attn1_fold1_kernel<<<dim3(N / 32, B), 512, 0, stream>>>(
        q1h, k1h, v1h, mask, Wf1, bf1, q2h, k2h, v2h, H, N, qmul2);
    // 3. d2 attention + fold2 -> pol/val QKV
    attn2_fold2_kernel<<<dim3(N / 32, B), 512, 0, stream>>>(
        q2h, k2h, v2h, mask, Wfp, bfp, Wfv, bfv,
        qph, kph, vph, qvh, kvh, vvh, H, N, qmul2);
    // 4. pol/val attention + head projections -> araw/craw
    attn3_heads_kernel<<<dim3(N / 32, B, 2), 512, 0, stream>>>(
        qph, kph, vph, qvh, kvh, vvh, mask,
        pol_wo, pol_bo, val_wo, val_bo, araw, craw, H, N);
    // 5. masked softmax + critic
    final_kernel<<<2 * B, 256, 0, stream>>>(
        araw, mask, craw, v2_w, v2_b, out_action, out_critic, N, B);
}